// Round 1
// baseline (947.389 us; speedup 1.0000x reference)
//
#include <hip/hip_runtime.h>
#include <hip/hip_bf16.h>
#include <cstdint>

// Problem dims
#define BB 16
#define CC 64
#define NN 512
#define TT 64
#define KCH 3
#define PP (BB*NN*TT)      // 524288 points
#define EPSB 1e-5f

typedef __bf16 bf16;
typedef __bf16 bf16x8 __attribute__((ext_vector_type(8)));
typedef __bf16 bf16x4 __attribute__((ext_vector_type(4)));
typedef float  f32x4  __attribute__((ext_vector_type(4)));

#define MFMA16(A,Bv,Cv) __builtin_amdgcn_mfma_f32_16x16x32_bf16((A),(Bv),(Cv),0,0,0)

// ---------------- prep: adjb[k][n][m] = bf16(adj[k][m][n]) ----------------
__global__ __launch_bounds__(256) void k_adjT(const float* __restrict__ adj,
                                              bf16* __restrict__ adjb){
  int idx = blockIdx.x*256 + threadIdx.x;          // over 3*512*512, exact grid
  int m = idx & 511, n = (idx >> 9) & 511, k = idx >> 18;
  adjb[idx] = (bf16)adj[((size_t)(k*512 + m))*512 + n];
}

// ---------------- prep: weights into MFMA B-fragment layout ----------------
// consumer reads: frag elem j of lane l at step ks, colfrag cf:
//   B[k = ks*32 + (l>>4)*8 + j][col = cf*16 + (l&15)]
// stored at wp[(((ks*4+cf)*64 + l)*8 + j]
__global__ __launch_bounds__(256) void k_wprep(const float* __restrict__ w1,
    const float* __restrict__ w2, const float* __restrict__ cw,
    const float* __restrict__ gw, const float* __restrict__ rw,
    bf16* __restrict__ w1p, bf16* __restrict__ w2p, bf16* __restrict__ cp,
    bf16* __restrict__ gp, bf16* __restrict__ rp){
  int tid = threadIdx.x;
  for (int e = tid; e < 6*2048; e += 256){          // K=192 groups (conv & cheb)
    int j = e&7, lane = (e>>3)&63, cf = (e>>9)&3, ks = e>>11;
    int k = ks*32 + (lane>>4)*8 + j, col = cf*16 + (lane&15);
    int kk = k >> 6, i = k & 63;                    // (dt|chebk, channel)
    w1p[e] = (bf16)w1[(col*64 + i)*3 + kk];         // w1[o][i][dt]
    w2p[e] = (bf16)w2[(col*64 + i)*3 + kk];
    cp[e]  = (bf16)cw[((size_t)kk*64 + i)*64 + col];// cheb_w[k][i][o]
  }
  for (int e = tid; e < 4*2048; e += 256){          // K=128 (gate)
    int j = e&7, lane = (e>>3)&63, cf = (e>>9)&3, ks = e>>11;
    int k = ks*32 + (lane>>4)*8 + j, col = cf*16 + (lane&15);
    gp[e] = (bf16)gw[col*128 + k];                  // gate_w[g][c]
  }
  for (int e = tid; e < 2*2048; e += 256){          // K=64 (res)
    int j = e&7, lane = (e>>3)&63, cf = (e>>9)&3, ks = e>>11;
    int k = ks*32 + (lane>>4)*8 + j, col = cf*16 + (lane&15);
    rp[e] = (bf16)rw[col*64 + k];                   // res_w[o][i]
  }
}

// ---------------- prep: xlb[b][n][t][i] = bf16(x[b][i][n][t]) --------------
__global__ __launch_bounds__(256) void k_xlb(const float* __restrict__ x,
                                             bf16* __restrict__ xlb){
  __shared__ float tile[64][65];
  int bn = blockIdx.x; int b = bn >> 9, n = bn & 511;
  int tid = threadIdx.x;
  const float* xp = x + ((size_t)(b*64)*512 + n)*64;   // x[b][0][n][0]
  for (int p = 0; p < 4; ++p){
    int q = p*256 + tid;                  // quad id 0..1023
    int i = q >> 4, tc = (q & 15)*4;
    float4 v = *reinterpret_cast<const float4*>(xp + (size_t)i*512*64 + tc);
    tile[i][tc+0] = v.x; tile[i][tc+1] = v.y; tile[i][tc+2] = v.z; tile[i][tc+3] = v.w;
  }
  __syncthreads();
  bf16* op = xlb + (size_t)bn*4096;
  for (int p = 0; p < 2; ++p){
    int v8 = p*256 + tid;                 // 0..511
    int t = v8 >> 3, ic = (v8 & 7)*8;
    bf16x8 o;
    #pragma unroll
    for (int e = 0; e < 8; ++e) o[e] = (bf16)tile[ic+e][t];
    *reinterpret_cast<bf16x8*>(op + t*64 + ic) = o;
  }
}

// ---------------- prep: xmt[b][t][i][m] = bf16(x[b][i][m][t]) --------------
// tile: i:16, m:64, t:16
__global__ __launch_bounds__(256) void k_xmt(const float* __restrict__ x,
                                             bf16* __restrict__ xmt){
  __shared__ bf16 lds[16][16][72];        // [t][i][m+pad]
  int bid = blockIdx.x;
  int t0 = (bid & 3)*16, m0 = ((bid>>2)&7)*64, i0 = ((bid>>5)&3)*16, b = bid>>7;
  int tid = threadIdx.x;
  int tq = tid & 3, m = tid >> 2;         // 4 t-quads x 64 m
  for (int i = 0; i < 16; ++i){
    float4 v = *reinterpret_cast<const float4*>(
        x + ((size_t)(b*64 + i0 + i)*512 + (m0 + m))*64 + t0 + tq*4);
    lds[tq*4+0][i][m] = (bf16)v.x; lds[tq*4+1][i][m] = (bf16)v.y;
    lds[tq*4+2][i][m] = (bf16)v.z; lds[tq*4+3][i][m] = (bf16)v.w;
  }
  __syncthreads();
  for (int p = 0; p < 8; ++p){
    int row = p*32 + (tid >> 3); int t = row >> 4, i = row & 15, mc = tid & 7;
    bf16x8 v = *reinterpret_cast<const bf16x8*>(&lds[t][i][mc*8]);
    *reinterpret_cast<bf16x8*>(
        xmt + ((size_t)((b*64 + t0 + t)*64) + i0 + i)*512 + m0 + mc*8) = v;
  }
}

// ---------------- temporal conv (1x3) as tall GEMM; optional BN+relu on load
// in/out layout: [point=(b,n,t)][64ch]; block = one (b,n), 64 t x 64 o
__global__ __launch_bounds__(256,4) void k_conv(const bf16* __restrict__ in,
    const bf16* __restrict__ wp, bf16* __restrict__ outp, float* __restrict__ part,
    const float* __restrict__ sc, const float* __restrict__ sh){
  int tid = threadIdx.x, w = tid >> 6, l = tid & 63, l15 = l & 15, lg = l >> 4;
  int blk = blockIdx.x;
  size_t rowbase = (size_t)blk * 64;
  const bf16* xr = in + rowbase * 64;
  int t = w*16 + l15;
  f32x4 acc[4] = {};
  #pragma unroll
  for (int ks = 0; ks < 6; ++ks){
    int dt = ks >> 1, kh = ks & 1;
    int ts = t + dt - 1;
    bf16x8 a = {};
    if (ts >= 0 && ts < 64){
      a = *reinterpret_cast<const bf16x8*>(xr + ts*64 + kh*32 + lg*8);
      if (sc){                                  // BN1+relu applied on load
        int i0 = kh*32 + lg*8;
        #pragma unroll
        for (int e = 0; e < 8; ++e){
          float f = (float)a[e]*sc[i0+e] + sh[i0+e];
          a[e] = (bf16)fmaxf(f, 0.f);
        }
      }
    }
    #pragma unroll
    for (int cf = 0; cf < 4; ++cf){
      bf16x8 bfr = *reinterpret_cast<const bf16x8*>(wp + ((ks*4 + cf)*64 + l)*8);
      acc[cf] = MFMA16(a, bfr, acc[cf]);
    }
  }
  __shared__ float ssum[4][4][16], ssq[4][4][16];
  #pragma unroll
  for (int cf = 0; cf < 4; ++cf){
    int o = cf*16 + l15;
    float s = 0.f, q = 0.f;
    #pragma unroll
    for (int r = 0; r < 4; ++r){
      float vv = acc[cf][r];
      int to = w*16 + lg*4 + r;
      outp[(rowbase + to)*64 + o] = (bf16)vv;
      s += vv; q += vv*vv;
    }
    s += __shfl_xor(s, 16); s += __shfl_xor(s, 32);
    q += __shfl_xor(q, 16); q += __shfl_xor(q, 32);
    if (lg == 0){ ssum[w][cf][l15] = s; ssq[w][cf][l15] = q; }
  }
  __syncthreads();
  if (tid < 64){
    int cf = tid >> 4, c = tid & 15;
    float s = ssum[0][cf][c]+ssum[1][cf][c]+ssum[2][cf][c]+ssum[3][cf][c];
    float q = ssq[0][cf][c]+ssq[1][cf][c]+ssq[2][cf][c]+ssq[3][cf][c];
    part[(size_t)blk*128 + tid*2]     = s;
    part[(size_t)blk*128 + tid*2 + 1] = q;
  }
}

// ---------------- BN stats finalize: partials -> scale/shift ----------------
__global__ __launch_bounds__(256) void k_stats(const float* __restrict__ part, int nb,
    const float* __restrict__ g, const float* __restrict__ be,
    float* __restrict__ sc, float* __restrict__ sh){
  int c = blockIdx.x, tid = threadIdx.x;
  float s = 0.f, q = 0.f;
  for (int i = tid; i < nb; i += 256){
    s += part[(size_t)i*128 + c*2];
    q += part[(size_t)i*128 + c*2 + 1];
  }
  __shared__ float rs[256], rq[256];
  rs[tid] = s; rq[tid] = q; __syncthreads();
  for (int st = 128; st > 0; st >>= 1){
    if (tid < st){ rs[tid] += rs[tid+st]; rq[tid] += rq[tid+st]; }
    __syncthreads();
  }
  if (tid == 0){
    float cnt = (float)PP;
    float mean = rs[0]/cnt, var = rq[0]/cnt - mean*mean;
    float r = rsqrtf(var + EPSB);
    sc[c] = g[c]*r;
    sh[c] = be[c] - mean*g[c]*r;
  }
}

// ---------------- GEMM1: v[k][n][b][t][i] = sum_m xmt[(b,t,i)][m]*adjb[k][n][m]
__global__ __launch_bounds__(256,3) void k_gemm1(const bf16* __restrict__ xmt,
    const bf16* __restrict__ adjb, bf16* __restrict__ v){
  int tid = threadIdx.x, w = tid >> 6, l = tid & 63, l15 = l & 15, lg = l >> 4;
  int nt = blockIdx.x, jt = blockIdx.y, k = blockIdx.z;
  int J0 = jt*128 + (w>>1)*64;
  int N0 = nt*128 + (w&1)*64;
  const bf16* ap = xmt + (size_t)J0*512;
  const bf16* bp = adjb + ((size_t)k*512 + N0)*512;
  f32x4 acc[4][4] = {};
  for (int m0 = 0; m0 < 512; m0 += 32){
    bf16x8 a[4], bb[4];
    #pragma unroll
    for (int rf = 0; rf < 4; ++rf)
      a[rf] = *reinterpret_cast<const bf16x8*>(ap + (size_t)(rf*16 + l15)*512 + m0 + lg*8);
    #pragma unroll
    for (int cf = 0; cf < 4; ++cf)
      bb[cf] = *reinterpret_cast<const bf16x8*>(bp + (size_t)(cf*16 + l15)*512 + m0 + lg*8);
    #pragma unroll
    for (int rf = 0; rf < 4; ++rf)
      #pragma unroll
      for (int cf = 0; cf < 4; ++cf)
        acc[rf][cf] = MFMA16(a[rf], bb[cf], acc[rf][cf]);
  }
  #pragma unroll
  for (int rf = 0; rf < 4; ++rf){
    int j = J0 + rf*16 + lg*4;                  // + reg r
    int b = j >> 12, tt = (j >> 6) & 63, i0 = j & 63;
    #pragma unroll
    for (int cf = 0; cf < 4; ++cf){
      int n = N0 + cf*16 + l15;
      bf16x4 o4;
      #pragma unroll
      for (int r = 0; r < 4; ++r) o4[r] = (bf16)acc[rf][cf][r];
      *reinterpret_cast<bf16x4*>(
          v + ((((size_t)k*512 + n)*16 + b)*64 + tt)*64 + i0) = o4;
    }
  }
}

// ---------------- GEMM2: spatial[(b,n,t)][o] = sum_{k,i} v * cheb + cheb_b --
__global__ __launch_bounds__(256,4) void k_gemm2(const bf16* __restrict__ v,
    const bf16* __restrict__ cp, const float* __restrict__ cb,
    bf16* __restrict__ spm){
  int tid = threadIdx.x, w = tid >> 6, l = tid & 63, l15 = l & 15, lg = l >> 4;
  int blk = blockIdx.x;
  int b = blk >> 9, n = blk & 511;
  size_t rowbase = (size_t)blk * 64;
  int t = w*16 + l15;
  f32x4 acc[4] = {};
  #pragma unroll
  for (int ks = 0; ks < 6; ++ks){
    int kk = ks >> 1, kh = ks & 1;
    bf16x8 a = *reinterpret_cast<const bf16x8*>(
        v + ((((size_t)kk*512 + n)*16 + b)*64 + t)*64 + kh*32 + lg*8);
    #pragma unroll
    for (int cf = 0; cf < 4; ++cf){
      bf16x8 bfr = *reinterpret_cast<const bf16x8*>(cp + ((ks*4 + cf)*64 + l)*8);
      acc[cf] = MFMA16(a, bfr, acc[cf]);
    }
  }
  int tb = w*16 + lg*4;
  #pragma unroll
  for (int cf = 0; cf < 4; ++cf){
    int o = cf*16 + l15;
    float cbo = cb[o];
    #pragma unroll
    for (int r = 0; r < 4; ++r)
      spm[(rowbase + tb + r)*64 + o] = (bf16)(acc[cf][r] + cbo);
  }
}

// ---------------- fusion: gate/res MFMA + combine; writes out_pre to d_out --
__global__ __launch_bounds__(256,4) void k_fusion(const bf16* __restrict__ spm,
    const bf16* __restrict__ t2, const bf16* __restrict__ xlb,
    const bf16* __restrict__ gp, const bf16* __restrict__ rp,
    const float* __restrict__ sc2, const float* __restrict__ sh2,
    const float* __restrict__ gateb, float* __restrict__ out,
    float* __restrict__ part){
  int tid = threadIdx.x, w = tid >> 6, l = tid & 63, l15 = l & 15, lg = l >> 4;
  int blk = blockIdx.x;
  int b = blk >> 9, n = blk & 511;
  size_t rowbase = (size_t)blk * 64;
  int t = w*16 + l15;
  f32x4 ag[4] = {}, ar[4] = {};
  #pragma unroll
  for (int ks = 0; ks < 4; ++ks){                 // gate: K=128 = [spatial|t2bn]
    bf16x8 a;
    if (ks < 2){
      a = *reinterpret_cast<const bf16x8*>(spm + (rowbase + t)*64 + ks*32 + lg*8);
    } else {
      int i0 = (ks-2)*32 + lg*8;
      bf16x8 raw = *reinterpret_cast<const bf16x8*>(t2 + (rowbase + t)*64 + i0);
      #pragma unroll
      for (int e = 0; e < 8; ++e){
        float f = (float)raw[e]*sc2[i0+e] + sh2[i0+e];
        a[e] = (bf16)fmaxf(f, 0.f);
      }
    }
    #pragma unroll
    for (int cf = 0; cf < 4; ++cf){
      bf16x8 bfr = *reinterpret_cast<const bf16x8*>(gp + ((ks*4 + cf)*64 + l)*8);
      ag[cf] = MFMA16(a, bfr, ag[cf]);
    }
  }
  #pragma unroll
  for (int ks = 0; ks < 2; ++ks){                 // res: K=64 on x
    bf16x8 a = *reinterpret_cast<const bf16x8*>(xlb + (rowbase + t)*64 + ks*32 + lg*8);
    #pragma unroll
    for (int cf = 0; cf < 4; ++cf){
      bf16x8 bfr = *reinterpret_cast<const bf16x8*>(rp + ((ks*4 + cf)*64 + l)*8);
      ar[cf] = MFMA16(a, bfr, ar[cf]);
    }
  }
  __shared__ float ssum[4][4][16], ssq[4][4][16];
  int tb = w*16 + lg*4;
  #pragma unroll
  for (int cf = 0; cf < 4; ++cf){
    int o = cf*16 + l15;
    float gb = gateb[o], sco = sc2[o], sho = sh2[o];
    float s = 0.f, q = 0.f;
    float4 ov;
    #pragma unroll
    for (int r = 0; r < 4; ++r){
      size_t row = rowbase + tb + r;
      float z = ag[cf][r] + gb;
      float g = 1.f/(1.f + __expf(-z));
      float spv = (float)spm[row*64 + o];
      float tv  = (float)t2[row*64 + o];
      tv = fmaxf(tv*sco + sho, 0.f);
      float val = g*spv + (1.f - g)*tv + ar[cf][r];
      (&ov.x)[r] = val;
      s += val; q += val*val;
    }
    *reinterpret_cast<float4*>(out + (((size_t)b*64 + o)*512 + n)*64 + tb) = ov;
    s += __shfl_xor(s, 16); s += __shfl_xor(s, 32);
    q += __shfl_xor(q, 16); q += __shfl_xor(q, 32);
    if (lg == 0){ ssum[w][cf][l15] = s; ssq[w][cf][l15] = q; }
  }
  __syncthreads();
  if (tid < 64){
    int cf = tid >> 4, c = tid & 15;
    float s = ssum[0][cf][c]+ssum[1][cf][c]+ssum[2][cf][c]+ssum[3][cf][c];
    float q = ssq[0][cf][c]+ssq[1][cf][c]+ssq[2][cf][c]+ssq[3][cf][c];
    part[(size_t)blk*128 + tid*2]     = s;
    part[(size_t)blk*128 + tid*2 + 1] = q;
  }
}

// ---------------- BN3 in-place on d_out ([b][o][n][t]) ----------------------
__global__ __launch_bounds__(256) void k_bn3(float* __restrict__ out,
    const float* __restrict__ sc, const float* __restrict__ sh){
  size_t total4 = (size_t)BB*CC*NN*TT/4;
  for (size_t i4 = (size_t)blockIdx.x*256 + threadIdx.x; i4 < total4;
       i4 += (size_t)gridDim.x*256){
    float4 v = reinterpret_cast<float4*>(out)[i4];
    int o = (int)((i4*4) >> 15) & 63;
    float a = sc[o], bsh = sh[o];
    v.x = v.x*a + bsh; v.y = v.y*a + bsh; v.z = v.z*a + bsh; v.w = v.w*a + bsh;
    reinterpret_cast<float4*>(out)[i4] = v;
  }
}

extern "C" void kernel_launch(void* const* d_in, const int* in_sizes, int n_in,
                              void* d_out, int out_size, void* d_ws, size_t ws_size,
                              hipStream_t stream){
  (void)in_sizes; (void)n_in; (void)out_size; (void)ws_size;
  const float* x   = (const float*)d_in[0];
  const float* adj = (const float*)d_in[1];
  const float* cw  = (const float*)d_in[2];
  const float* cb  = (const float*)d_in[3];
  const float* w1  = (const float*)d_in[4];
  // d_in[5] = b1 (cancels in BN1)
  const float* g1  = (const float*)d_in[6];
  const float* be1 = (const float*)d_in[7];
  const float* w2  = (const float*)d_in[8];
  // d_in[9] = b2 (cancels in BN2)
  const float* g2  = (const float*)d_in[10];
  const float* be2 = (const float*)d_in[11];
  const float* gw  = (const float*)d_in[12];
  const float* gb  = (const float*)d_in[13];
  const float* rw  = (const float*)d_in[14];
  // d_in[15] = res_b (cancels in BN3)
  const float* g3  = (const float*)d_in[16];
  const float* be3 = (const float*)d_in[17];
  float* out = (float*)d_out;

  char* ws = (char*)d_ws;
  size_t off = 0;
  auto alloc = [&](size_t bytes)->char*{
    char* p = ws + off; off += (bytes + 255) & ~(size_t)255; return p;
  };
  bf16* xlb  = (bf16*)alloc((size_t)PP*64*2);        // 67MB channel-last x
  bf16* xmt  = (bf16*)alloc((size_t)PP*64*2);        // 67MB m-contiguous x
  bf16* v    = (bf16*)alloc((size_t)KCH*PP*64*2);    // 201MB; t1 aliases front
  bf16* t1   = v;                                    // alias (dead before gemm1)
  bf16* t2   = (bf16*)alloc((size_t)PP*64*2);        // 67MB
  bf16* spm  = xmt;                                  // alias (xmt dead after gemm1)
  bf16* adjb = (bf16*)alloc((size_t)KCH*512*512*2);
  bf16* w1p  = (bf16*)alloc(6*2048*2);
  bf16* w2p  = (bf16*)alloc(6*2048*2);
  bf16* cp   = (bf16*)alloc(6*2048*2);
  bf16* gp   = (bf16*)alloc(4*2048*2);
  bf16* rp   = (bf16*)alloc(2*2048*2);
  float* part = (float*)alloc((size_t)8192*128*4);   // shared partials (sequential)
  float* s1sc = (float*)alloc(256); float* s1sh = (float*)alloc(256);
  float* s2sc = (float*)alloc(256); float* s2sh = (float*)alloc(256);
  float* s3sc = (float*)alloc(256); float* s3sh = (float*)alloc(256);

  k_adjT <<<dim3(3072), dim3(256), 0, stream>>>(adj, adjb);
  k_wprep<<<dim3(1),    dim3(256), 0, stream>>>(w1, w2, cw, gw, rw, w1p, w2p, cp, gp, rp);
  k_xlb  <<<dim3(8192), dim3(256), 0, stream>>>(x, xlb);
  k_xmt  <<<dim3(2048), dim3(256), 0, stream>>>(x, xmt);

  k_conv <<<dim3(8192), dim3(256), 0, stream>>>(xlb, w1p, t1, part, nullptr, nullptr);
  k_stats<<<dim3(64),   dim3(256), 0, stream>>>(part, 8192, g1, be1, s1sc, s1sh);
  k_conv <<<dim3(8192), dim3(256), 0, stream>>>(t1, w2p, t2, part, s1sc, s1sh);
  k_stats<<<dim3(64),   dim3(256), 0, stream>>>(part, 8192, g2, be2, s2sc, s2sh);

  k_gemm1<<<dim3(4,512,3), dim3(256), 0, stream>>>(xmt, adjb, v);
  k_gemm2<<<dim3(8192), dim3(256), 0, stream>>>(v, cp, cb, spm);

  k_fusion<<<dim3(8192), dim3(256), 0, stream>>>(spm, t2, xlb, gp, rp,
                                                 s2sc, s2sh, gb, out, part);
  k_stats<<<dim3(64),   dim3(256), 0, stream>>>(part, 8192, g3, be3, s3sc, s3sh);
  k_bn3  <<<dim3(2048), dim3(256), 0, stream>>>(out, s3sc, s3sh);
}

// Round 2
// 713.295 us; speedup vs baseline: 1.3282x; 1.3282x over previous
//
#include <hip/hip_runtime.h>
#include <hip/hip_bf16.h>
#include <cstdint>

// Problem dims
#define BB 16
#define CC 64
#define NN 512
#define TT 64
#define KCH 3
#define PP (BB*NN*TT)      // 524288 points
#define EPSB 1e-5f

typedef __bf16 bf16;
typedef __bf16 bf16x8 __attribute__((ext_vector_type(8)));
typedef __bf16 bf16x4 __attribute__((ext_vector_type(4)));
typedef float  f32x4  __attribute__((ext_vector_type(4)));

#define MFMA16(A,Bv,Cv) __builtin_amdgcn_mfma_f32_16x16x32_bf16((A),(Bv),(Cv),0,0,0)

__device__ __forceinline__ void gload_lds16(const bf16* g, bf16* l){
  __builtin_amdgcn_global_load_lds(
      (const __attribute__((address_space(1))) void*)g,
      (__attribute__((address_space(3))) void*)l, 16, 0, 0);
}

// ---------------- prep: adjb[k][n][m] = bf16(adj[k][m][n]) ----------------
__global__ __launch_bounds__(256) void k_adjT(const float* __restrict__ adj,
                                              bf16* __restrict__ adjb){
  int idx = blockIdx.x*256 + threadIdx.x;          // over 3*512*512, exact grid
  int m = idx & 511, n = (idx >> 9) & 511, k = idx >> 18;
  adjb[idx] = (bf16)adj[((size_t)(k*512 + m))*512 + n];
}

// ---------------- prep: weights into MFMA B-fragment layout ----------------
// consumer reads: frag elem j of lane l at step ks, colfrag cf:
//   B[k = ks*32 + (l>>4)*8 + j][col = cf*16 + (l&15)]
// stored at wp[(((ks*4+cf)*64 + l)*8 + j]
__global__ __launch_bounds__(256) void k_wprep(const float* __restrict__ w1,
    const float* __restrict__ w2, const float* __restrict__ cw,
    const float* __restrict__ gw, const float* __restrict__ rw,
    bf16* __restrict__ w1p, bf16* __restrict__ w2p, bf16* __restrict__ cp,
    bf16* __restrict__ gp, bf16* __restrict__ rp){
  int tid = threadIdx.x;
  for (int e = tid; e < 6*2048; e += 256){          // K=192 groups (conv & cheb)
    int j = e&7, lane = (e>>3)&63, cf = (e>>9)&3, ks = e>>11;
    int k = ks*32 + (lane>>4)*8 + j, col = cf*16 + (lane&15);
    int kk = k >> 6, i = k & 63;                    // (dt|chebk, channel)
    w1p[e] = (bf16)w1[(col*64 + i)*3 + kk];         // w1[o][i][dt]
    w2p[e] = (bf16)w2[(col*64 + i)*3 + kk];
    cp[e]  = (bf16)cw[((size_t)kk*64 + i)*64 + col];// cheb_w[k][i][o]
  }
  for (int e = tid; e < 4*2048; e += 256){          // K=128 (gate)
    int j = e&7, lane = (e>>3)&63, cf = (e>>9)&3, ks = e>>11;
    int k = ks*32 + (lane>>4)*8 + j, col = cf*16 + (lane&15);
    gp[e] = (bf16)gw[col*128 + k];                  // gate_w[g][c]
  }
  for (int e = tid; e < 2*2048; e += 256){          // K=64 (res)
    int j = e&7, lane = (e>>3)&63, cf = (e>>9)&3, ks = e>>11;
    int k = ks*32 + (lane>>4)*8 + j, col = cf*16 + (lane&15);
    rp[e] = (bf16)rw[col*64 + k];                   // res_w[o][i]
  }
}

// ---------------- prep: xlb[b][n][t][i] = bf16(x[b][i][n][t]) --------------
__global__ __launch_bounds__(256) void k_xlb(const float* __restrict__ x,
                                             bf16* __restrict__ xlb){
  __shared__ float tile[64][65];
  int bn = blockIdx.x; int b = bn >> 9, n = bn & 511;
  int tid = threadIdx.x;
  const float* xp = x + ((size_t)(b*64)*512 + n)*64;   // x[b][0][n][0]
  for (int p = 0; p < 4; ++p){
    int q = p*256 + tid;                  // quad id 0..1023
    int i = q >> 4, tc = (q & 15)*4;
    float4 v = *reinterpret_cast<const float4*>(xp + (size_t)i*512*64 + tc);
    tile[i][tc+0] = v.x; tile[i][tc+1] = v.y; tile[i][tc+2] = v.z; tile[i][tc+3] = v.w;
  }
  __syncthreads();
  bf16* op = xlb + (size_t)bn*4096;
  for (int p = 0; p < 2; ++p){
    int v8 = p*256 + tid;                 // 0..511
    int t = v8 >> 3, ic = (v8 & 7)*8;
    bf16x8 o;
    #pragma unroll
    for (int e = 0; e < 8; ++e) o[e] = (bf16)tile[ic+e][t];
    *reinterpret_cast<bf16x8*>(op + t*64 + ic) = o;
  }
}

// ---------------- prep: xmt[b][t][i][m] = bf16(x[b][i][m][t]) --------------
// tile: i:16, m:64, t:16
__global__ __launch_bounds__(256) void k_xmt(const float* __restrict__ x,
                                             bf16* __restrict__ xmt){
  __shared__ bf16 lds[16][16][72];        // [t][i][m+pad]
  int bid = blockIdx.x;
  int t0 = (bid & 3)*16, m0 = ((bid>>2)&7)*64, i0 = ((bid>>5)&3)*16, b = bid>>7;
  int tid = threadIdx.x;
  int tq = tid & 3, m = tid >> 2;         // 4 t-quads x 64 m
  for (int i = 0; i < 16; ++i){
    float4 v = *reinterpret_cast<const float4*>(
        x + ((size_t)(b*64 + i0 + i)*512 + (m0 + m))*64 + t0 + tq*4);
    lds[tq*4+0][i][m] = (bf16)v.x; lds[tq*4+1][i][m] = (bf16)v.y;
    lds[tq*4+2][i][m] = (bf16)v.z; lds[tq*4+3][i][m] = (bf16)v.w;
  }
  __syncthreads();
  for (int p = 0; p < 8; ++p){
    int row = p*32 + (tid >> 3); int t = row >> 4, i = row & 15, mc = tid & 7;
    bf16x8 v = *reinterpret_cast<const bf16x8*>(&lds[t][i][mc*8]);
    *reinterpret_cast<bf16x8*>(
        xmt + ((size_t)((b*64 + t0 + t)*64) + i0 + i)*512 + m0 + mc*8) = v;
  }
}

// ---------------- temporal conv (1x3) as tall GEMM; optional BN+relu on load
// in/out layout: [point=(b,n,t)][64ch]; block = one (b,n), 64 t x 64 o
__global__ __launch_bounds__(256,4) void k_conv(const bf16* __restrict__ in,
    const bf16* __restrict__ wp, bf16* __restrict__ outp, float* __restrict__ part,
    const float* __restrict__ sc, const float* __restrict__ sh){
  int tid = threadIdx.x, w = tid >> 6, l = tid & 63, l15 = l & 15, lg = l >> 4;
  int blk = blockIdx.x;
  size_t rowbase = (size_t)blk * 64;
  const bf16* xr = in + rowbase * 64;
  int t = w*16 + l15;
  f32x4 acc[4] = {};
  #pragma unroll
  for (int ks = 0; ks < 6; ++ks){
    int dt = ks >> 1, kh = ks & 1;
    int ts = t + dt - 1;
    bf16x8 a = {};
    if (ts >= 0 && ts < 64){
      a = *reinterpret_cast<const bf16x8*>(xr + ts*64 + kh*32 + lg*8);
      if (sc){                                  // BN1+relu applied on load
        int i0 = kh*32 + lg*8;
        #pragma unroll
        for (int e = 0; e < 8; ++e){
          float f = (float)a[e]*sc[i0+e] + sh[i0+e];
          a[e] = (bf16)fmaxf(f, 0.f);
        }
      }
    }
    #pragma unroll
    for (int cf = 0; cf < 4; ++cf){
      bf16x8 bfr = *reinterpret_cast<const bf16x8*>(wp + ((ks*4 + cf)*64 + l)*8);
      acc[cf] = MFMA16(a, bfr, acc[cf]);
    }
  }
  __shared__ float ssum[4][4][16], ssq[4][4][16];
  #pragma unroll
  for (int cf = 0; cf < 4; ++cf){
    int o = cf*16 + l15;
    float s = 0.f, q = 0.f;
    #pragma unroll
    for (int r = 0; r < 4; ++r){
      float vv = acc[cf][r];
      int to = w*16 + lg*4 + r;
      outp[(rowbase + to)*64 + o] = (bf16)vv;
      s += vv; q += vv*vv;
    }
    s += __shfl_xor(s, 16); s += __shfl_xor(s, 32);
    q += __shfl_xor(q, 16); q += __shfl_xor(q, 32);
    if (lg == 0){ ssum[w][cf][l15] = s; ssq[w][cf][l15] = q; }
  }
  __syncthreads();
  if (tid < 64){
    int cf = tid >> 4, c = tid & 15;
    float s = ssum[0][cf][c]+ssum[1][cf][c]+ssum[2][cf][c]+ssum[3][cf][c];
    float q = ssq[0][cf][c]+ssq[1][cf][c]+ssq[2][cf][c]+ssq[3][cf][c];
    part[(size_t)blk*128 + tid*2]     = s;
    part[(size_t)blk*128 + tid*2 + 1] = q;
  }
}

// ---------------- BN stats finalize: partials -> scale/shift ----------------
__global__ __launch_bounds__(256) void k_stats(const float* __restrict__ part, int nb,
    const float* __restrict__ g, const float* __restrict__ be,
    float* __restrict__ sc, float* __restrict__ sh){
  int c = blockIdx.x, tid = threadIdx.x;
  float s = 0.f, q = 0.f;
  for (int i = tid; i < nb; i += 256){
    s += part[(size_t)i*128 + c*2];
    q += part[(size_t)i*128 + c*2 + 1];
  }
  __shared__ float rs[256], rq[256];
  rs[tid] = s; rq[tid] = q; __syncthreads();
  for (int st = 128; st > 0; st >>= 1){
    if (tid < st){ rs[tid] += rs[tid+st]; rq[tid] += rq[tid+st]; }
    __syncthreads();
  }
  if (tid == 0){
    float cnt = (float)PP;
    float mean = rs[0]/cnt, var = rq[0]/cnt - mean*mean;
    float r = rsqrtf(var + EPSB);
    sc[c] = g[c]*r;
    sh[c] = be[c] - mean*g[c]*r;
  }
}

// ---------------- GEMM1: v[k][n][b][t][i] = sum_m xmt[(b,t,i)][m]*adjb[k][n][m]
// 128x128 tile, BK=32, double-buffered LDS via global_load_lds(16B),
// chunk-XOR swizzle (c ^= row&3) so ds_read_b128 is 2-way (free) not 8-way.
__global__ __launch_bounds__(256) void k_gemm1(const bf16* __restrict__ xmt,
    const bf16* __restrict__ adjb, bf16* __restrict__ v){
  __shared__ bf16 As[2][128*32];
  __shared__ bf16 Bs[2][128*32];

  int tid = threadIdx.x, w = tid >> 6, l = tid & 63, l15 = l & 15, lg = l >> 4;
  int wr = w >> 1, wc = w & 1;

  // bijective XCD swizzle over 6144 blocks; nt innermost (A-panel shared by 4)
  int orig = blockIdx.x;
  int wg = (orig & 7) * 768 + (orig >> 3);
  int k  = wg >> 11;                 // /2048
  int rem = wg & 2047;
  int jt = rem >> 2, nt = rem & 3;
  int J0 = jt*128, N0 = nt*128;

  const bf16* aglob = xmt + (size_t)J0*512;
  const bf16* bglob = adjb + ((size_t)k*512 + N0)*512;

  // staging: thread tid in round p handles chunk idx = p*256+tid of 512 chunks
  // chunk idx -> tile (r = idx>>2, c = idx&3); global col chunk = c ^ (r&3)
  int sr0 = (tid*4 + 0*1024) >> 2;   // not used; compute per-round below
  (void)sr0;

  auto stage = [&](int buf, int m0){
    #pragma unroll
    for (int p = 0; p < 2; ++p){
      int idx = p*256 + tid;
      int r = idx >> 2, c = idx & 3;
      int cg = c ^ (r & 3);
      gload_lds16(aglob + (size_t)r*512 + m0 + cg*8,
                  &As[buf][(p*256 + w*64)*8]);
      gload_lds16(bglob + (size_t)r*512 + m0 + cg*8,
                  &Bs[buf][(p*256 + w*64)*8]);
    }
  };

  f32x4 acc[4][4] = {};

  stage(0, 0);
  __syncthreads();

  int buf = 0;
  for (int ks = 0; ks < 16; ++ks){
    if (ks < 15) stage(buf ^ 1, (ks+1)*32);

    bf16x8 a[4], bb[4];
    #pragma unroll
    for (int rf = 0; rf < 4; ++rf){
      int row = wr*64 + rf*16 + l15;
      a[rf] = *reinterpret_cast<const bf16x8*>(
          &As[buf][row*32 + ((lg ^ (row & 3))*8)]);
    }
    #pragma unroll
    for (int cf = 0; cf < 4; ++cf){
      int row = wc*64 + cf*16 + l15;
      bb[cf] = *reinterpret_cast<const bf16x8*>(
          &Bs[buf][row*32 + ((lg ^ (row & 3))*8)]);
    }
    #pragma unroll
    for (int rf = 0; rf < 4; ++rf)
      #pragma unroll
      for (int cf = 0; cf < 4; ++cf)
        acc[rf][cf] = MFMA16(a[rf], bb[cf], acc[rf][cf]);

    __syncthreads();
    buf ^= 1;
  }

  #pragma unroll
  for (int rf = 0; rf < 4; ++rf){
    int j = J0 + wr*64 + rf*16 + lg*4;          // + reg r
    int b = j >> 12, tt = (j >> 6) & 63, i0 = j & 63;
    #pragma unroll
    for (int cf = 0; cf < 4; ++cf){
      int n = N0 + wc*64 + cf*16 + l15;
      bf16x4 o4;
      #pragma unroll
      for (int r = 0; r < 4; ++r) o4[r] = (bf16)acc[rf][cf][r];
      *reinterpret_cast<bf16x4*>(
          v + ((((size_t)k*512 + n)*16 + b)*64 + tt)*64 + i0) = o4;
    }
  }
}

// ---------------- GEMM2: spatial[(b,n,t)][o] = sum_{k,i} v * cheb + cheb_b --
__global__ __launch_bounds__(256,4) void k_gemm2(const bf16* __restrict__ v,
    const bf16* __restrict__ cp, const float* __restrict__ cb,
    bf16* __restrict__ spm){
  int tid = threadIdx.x, w = tid >> 6, l = tid & 63, l15 = l & 15, lg = l >> 4;
  int blk = blockIdx.x;
  int b = blk >> 9, n = blk & 511;
  size_t rowbase = (size_t)blk * 64;
  int t = w*16 + l15;
  f32x4 acc[4] = {};
  #pragma unroll
  for (int ks = 0; ks < 6; ++ks){
    int kk = ks >> 1, kh = ks & 1;
    bf16x8 a = *reinterpret_cast<const bf16x8*>(
        v + ((((size_t)kk*512 + n)*16 + b)*64 + t)*64 + kh*32 + lg*8);
    #pragma unroll
    for (int cf = 0; cf < 4; ++cf){
      bf16x8 bfr = *reinterpret_cast<const bf16x8*>(cp + ((ks*4 + cf)*64 + l)*8);
      acc[cf] = MFMA16(a, bfr, acc[cf]);
    }
  }
  int tb = w*16 + lg*4;
  #pragma unroll
  for (int cf = 0; cf < 4; ++cf){
    int o = cf*16 + l15;
    float cbo = cb[o];
    #pragma unroll
    for (int r = 0; r < 4; ++r)
      spm[(rowbase + tb + r)*64 + o] = (bf16)(acc[cf][r] + cbo);
  }
}

// ---------------- fusion: gate/res MFMA + combine; writes out_pre to d_out --
__global__ __launch_bounds__(256,4) void k_fusion(const bf16* __restrict__ spm,
    const bf16* __restrict__ t2, const bf16* __restrict__ xlb,
    const bf16* __restrict__ gp, const bf16* __restrict__ rp,
    const float* __restrict__ sc2, const float* __restrict__ sh2,
    const float* __restrict__ gateb, float* __restrict__ out,
    float* __restrict__ part){
  int tid = threadIdx.x, w = tid >> 6, l = tid & 63, l15 = l & 15, lg = l >> 4;
  int blk = blockIdx.x;
  int b = blk >> 9, n = blk & 511;
  size_t rowbase = (size_t)blk * 64;
  int t = w*16 + l15;
  f32x4 ag[4] = {}, ar[4] = {};
  #pragma unroll
  for (int ks = 0; ks < 4; ++ks){                 // gate: K=128 = [spatial|t2bn]
    bf16x8 a;
    if (ks < 2){
      a = *reinterpret_cast<const bf16x8*>(spm + (rowbase + t)*64 + ks*32 + lg*8);
    } else {
      int i0 = (ks-2)*32 + lg*8;
      bf16x8 raw = *reinterpret_cast<const bf16x8*>(t2 + (rowbase + t)*64 + i0);
      #pragma unroll
      for (int e = 0; e < 8; ++e){
        float f = (float)raw[e]*sc2[i0+e] + sh2[i0+e];
        a[e] = (bf16)fmaxf(f, 0.f);
      }
    }
    #pragma unroll
    for (int cf = 0; cf < 4; ++cf){
      bf16x8 bfr = *reinterpret_cast<const bf16x8*>(gp + ((ks*4 + cf)*64 + l)*8);
      ag[cf] = MFMA16(a, bfr, ag[cf]);
    }
  }
  #pragma unroll
  for (int ks = 0; ks < 2; ++ks){                 // res: K=64 on x
    bf16x8 a = *reinterpret_cast<const bf16x8*>(xlb + (rowbase + t)*64 + ks*32 + lg*8);
    #pragma unroll
    for (int cf = 0; cf < 4; ++cf){
      bf16x8 bfr = *reinterpret_cast<const bf16x8*>(rp + ((ks*4 + cf)*64 + l)*8);
      ar[cf] = MFMA16(a, bfr, ar[cf]);
    }
  }
  __shared__ float ssum[4][4][16], ssq[4][4][16];
  int tb = w*16 + lg*4;
  #pragma unroll
  for (int cf = 0; cf < 4; ++cf){
    int o = cf*16 + l15;
    float gb = gateb[o], sco = sc2[o], sho = sh2[o];
    float s = 0.f, q = 0.f;
    float4 ov;
    #pragma unroll
    for (int r = 0; r < 4; ++r){
      size_t row = rowbase + tb + r;
      float z = ag[cf][r] + gb;
      float g = 1.f/(1.f + __expf(-z));
      float spv = (float)spm[row*64 + o];
      float tv  = (float)t2[row*64 + o];
      tv = fmaxf(tv*sco + sho, 0.f);
      float val = g*spv + (1.f - g)*tv + ar[cf][r];
      (&ov.x)[r] = val;
      s += val; q += val*val;
    }
    *reinterpret_cast<float4*>(out + (((size_t)b*64 + o)*512 + n)*64 + tb) = ov;
    s += __shfl_xor(s, 16); s += __shfl_xor(s, 32);
    q += __shfl_xor(q, 16); q += __shfl_xor(q, 32);
    if (lg == 0){ ssum[w][cf][l15] = s; ssq[w][cf][l15] = q; }
  }
  __syncthreads();
  if (tid < 64){
    int cf = tid >> 4, c = tid & 15;
    float s = ssum[0][cf][c]+ssum[1][cf][c]+ssum[2][cf][c]+ssum[3][cf][c];
    float q = ssq[0][cf][c]+ssq[1][cf][c]+ssq[2][cf][c]+ssq[3][cf][c];
    part[(size_t)blk*128 + tid*2]     = s;
    part[(size_t)blk*128 + tid*2 + 1] = q;
  }
}

// ---------------- BN3 in-place on d_out ([b][o][n][t]) ----------------------
__global__ __launch_bounds__(256) void k_bn3(float* __restrict__ out,
    const float* __restrict__ sc, const float* __restrict__ sh){
  size_t total4 = (size_t)BB*CC*NN*TT/4;
  for (size_t i4 = (size_t)blockIdx.x*256 + threadIdx.x; i4 < total4;
       i4 += (size_t)gridDim.x*256){
    float4 v = reinterpret_cast<float4*>(out)[i4];
    int o = (int)((i4*4) >> 15) & 63;
    float a = sc[o], bsh = sh[o];
    v.x = v.x*a + bsh; v.y = v.y*a + bsh; v.z = v.z*a + bsh; v.w = v.w*a + bsh;
    reinterpret_cast<float4*>(out)[i4] = v;
  }
}

extern "C" void kernel_launch(void* const* d_in, const int* in_sizes, int n_in,
                              void* d_out, int out_size, void* d_ws, size_t ws_size,
                              hipStream_t stream){
  (void)in_sizes; (void)n_in; (void)out_size; (void)ws_size;
  const float* x   = (const float*)d_in[0];
  const float* adj = (const float*)d_in[1];
  const float* cw  = (const float*)d_in[2];
  const float* cb  = (const float*)d_in[3];
  const float* w1  = (const float*)d_in[4];
  // d_in[5] = b1 (cancels in BN1)
  const float* g1  = (const float*)d_in[6];
  const float* be1 = (const float*)d_in[7];
  const float* w2  = (const float*)d_in[8];
  // d_in[9] = b2 (cancels in BN2)
  const float* g2  = (const float*)d_in[10];
  const float* be2 = (const float*)d_in[11];
  const float* gw  = (const float*)d_in[12];
  const float* gb  = (const float*)d_in[13];
  const float* rw  = (const float*)d_in[14];
  // d_in[15] = res_b (cancels in BN3)
  const float* g3  = (const float*)d_in[16];
  const float* be3 = (const float*)d_in[17];
  float* out = (float*)d_out;

  char* ws = (char*)d_ws;
  size_t off = 0;
  auto alloc = [&](size_t bytes)->char*{
    char* p = ws + off; off += (bytes + 255) & ~(size_t)255; return p;
  };
  bf16* xlb  = (bf16*)alloc((size_t)PP*64*2);        // 67MB channel-last x
  bf16* xmt  = (bf16*)alloc((size_t)PP*64*2);        // 67MB m-contiguous x
  bf16* v    = (bf16*)alloc((size_t)KCH*PP*64*2);    // 201MB; t1 aliases front
  bf16* t1   = v;                                    // alias (dead before gemm1)
  bf16* t2   = (bf16*)alloc((size_t)PP*64*2);        // 67MB
  bf16* spm  = xmt;                                  // alias (xmt dead after gemm1)
  bf16* adjb = (bf16*)alloc((size_t)KCH*512*512*2);
  bf16* w1p  = (bf16*)alloc(6*2048*2);
  bf16* w2p  = (bf16*)alloc(6*2048*2);
  bf16* cp   = (bf16*)alloc(6*2048*2);
  bf16* gp   = (bf16*)alloc(4*2048*2);
  bf16* rp   = (bf16*)alloc(2*2048*2);
  float* part = (float*)alloc((size_t)8192*128*4);   // shared partials (sequential)
  float* s1sc = (float*)alloc(256); float* s1sh = (float*)alloc(256);
  float* s2sc = (float*)alloc(256); float* s2sh = (float*)alloc(256);
  float* s3sc = (float*)alloc(256); float* s3sh = (float*)alloc(256);

  k_adjT <<<dim3(3072), dim3(256), 0, stream>>>(adj, adjb);
  k_wprep<<<dim3(1),    dim3(256), 0, stream>>>(w1, w2, cw, gw, rw, w1p, w2p, cp, gp, rp);
  k_xlb  <<<dim3(8192), dim3(256), 0, stream>>>(x, xlb);
  k_xmt  <<<dim3(2048), dim3(256), 0, stream>>>(x, xmt);

  k_conv <<<dim3(8192), dim3(256), 0, stream>>>(xlb, w1p, t1, part, nullptr, nullptr);
  k_stats<<<dim3(64),   dim3(256), 0, stream>>>(part, 8192, g1, be1, s1sc, s1sh);
  k_conv <<<dim3(8192), dim3(256), 0, stream>>>(t1, w2p, t2, part, s1sc, s1sh);
  k_stats<<<dim3(64),   dim3(256), 0, stream>>>(part, 8192, g2, be2, s2sc, s2sh);

  k_gemm1<<<dim3(6144), dim3(256), 0, stream>>>(xmt, adjb, v);
  k_gemm2<<<dim3(8192), dim3(256), 0, stream>>>(v, cp, cb, spm);

  k_fusion<<<dim3(8192), dim3(256), 0, stream>>>(spm, t2, xlb, gp, rp,
                                                 s2sc, s2sh, gb, out, part);
  k_stats<<<dim3(64),   dim3(256), 0, stream>>>(part, 8192, g3, be3, s3sc, s3sh);
  k_bn3  <<<dim3(2048), dim3(256), 0, stream>>>(out, s3sc, s3sh);
}

// Round 3
// 623.959 us; speedup vs baseline: 1.5184x; 1.1432x over previous
//
#include <hip/hip_runtime.h>
#include <hip/hip_bf16.h>
#include <cstdint>

// Problem dims
#define BB 16
#define CC 64
#define NN 512
#define TT 64
#define KCH 3
#define PP (BB*NN*TT)      // 524288 points
#define EPSB 1e-5f

typedef __bf16 bf16;
typedef __bf16 bf16x8 __attribute__((ext_vector_type(8)));
typedef __bf16 bf16x4 __attribute__((ext_vector_type(4)));
typedef float  f32x4  __attribute__((ext_vector_type(4)));

#define MFMA16(A,Bv,Cv) __builtin_amdgcn_mfma_f32_16x16x32_bf16((A),(Bv),(Cv),0,0,0)

__device__ __forceinline__ void gload_lds16(const bf16* g, bf16* l){
  __builtin_amdgcn_global_load_lds(
      (const __attribute__((address_space(1))) void*)g,
      (__attribute__((address_space(3))) void*)l, 16, 0, 0);
}

// ---------------- prep: adjb[k][n][m] = bf16(adj[k][m][n]) ----------------
__global__ __launch_bounds__(256) void k_adjT(const float* __restrict__ adj,
                                              bf16* __restrict__ adjb){
  int idx = blockIdx.x*256 + threadIdx.x;          // over 3*512*512, exact grid
  int m = idx & 511, n = (idx >> 9) & 511, k = idx >> 18;
  adjb[idx] = (bf16)adj[((size_t)(k*512 + m))*512 + n];
}

// ---------------- prep: weights into MFMA B-fragment layout ----------------
// consumer reads: frag elem j of lane l at step ks, colfrag cf:
//   B[k = ks*32 + (l>>4)*8 + j][col = cf*16 + (l&15)]
// stored at wp[(((ks*4+cf)*64 + l)*8 + j]
__global__ __launch_bounds__(256) void k_wprep(const float* __restrict__ w1,
    const float* __restrict__ w2, const float* __restrict__ cw,
    const float* __restrict__ gw, const float* __restrict__ rw,
    bf16* __restrict__ w1p, bf16* __restrict__ w2p, bf16* __restrict__ cp,
    bf16* __restrict__ gp, bf16* __restrict__ rp){
  int tid = threadIdx.x;
  for (int e = tid; e < 6*2048; e += 256){          // K=192 groups (conv & cheb)
    int j = e&7, lane = (e>>3)&63, cf = (e>>9)&3, ks = e>>11;
    int k = ks*32 + (lane>>4)*8 + j, col = cf*16 + (lane&15);
    int kk = k >> 6, i = k & 63;                    // (dt|chebk, channel)
    w1p[e] = (bf16)w1[(col*64 + i)*3 + kk];         // w1[o][i][dt]
    w2p[e] = (bf16)w2[(col*64 + i)*3 + kk];
    cp[e]  = (bf16)cw[((size_t)kk*64 + i)*64 + col];// cheb_w[k][i][o]
  }
  for (int e = tid; e < 4*2048; e += 256){          // K=128 (gate)
    int j = e&7, lane = (e>>3)&63, cf = (e>>9)&3, ks = e>>11;
    int k = ks*32 + (lane>>4)*8 + j, col = cf*16 + (lane&15);
    gp[e] = (bf16)gw[col*128 + k];                  // gate_w[g][c]
  }
  for (int e = tid; e < 2*2048; e += 256){          // K=64 (res)
    int j = e&7, lane = (e>>3)&63, cf = (e>>9)&3, ks = e>>11;
    int k = ks*32 + (lane>>4)*8 + j, col = cf*16 + (lane&15);
    rp[e] = (bf16)rw[col*64 + k];                   // res_w[o][i]
  }
}

// ---------------- prep: xlb[b][n][t][i] = bf16(x[b][i][n][t]) --------------
__global__ __launch_bounds__(256) void k_xlb(const float* __restrict__ x,
                                             bf16* __restrict__ xlb){
  __shared__ float tile[64][65];
  int bn = blockIdx.x; int b = bn >> 9, n = bn & 511;
  int tid = threadIdx.x;
  const float* xp = x + ((size_t)(b*64)*512 + n)*64;   // x[b][0][n][0]
  for (int p = 0; p < 4; ++p){
    int q = p*256 + tid;                  // quad id 0..1023
    int i = q >> 4, tc = (q & 15)*4;
    float4 v = *reinterpret_cast<const float4*>(xp + (size_t)i*512*64 + tc);
    tile[i][tc+0] = v.x; tile[i][tc+1] = v.y; tile[i][tc+2] = v.z; tile[i][tc+3] = v.w;
  }
  __syncthreads();
  bf16* op = xlb + (size_t)bn*4096;
  for (int p = 0; p < 2; ++p){
    int v8 = p*256 + tid;                 // 0..511
    int t = v8 >> 3, ic = (v8 & 7)*8;
    bf16x8 o;
    #pragma unroll
    for (int e = 0; e < 8; ++e) o[e] = (bf16)tile[ic+e][t];
    *reinterpret_cast<bf16x8*>(op + t*64 + ic) = o;
  }
}

// ---------------- prep: xmt[b][t][i][m] = bf16(x[b][i][m][t]) --------------
// tile: i:16, m:64, t:16
__global__ __launch_bounds__(256) void k_xmt(const float* __restrict__ x,
                                             bf16* __restrict__ xmt){
  __shared__ bf16 lds[16][16][72];        // [t][i][m+pad]
  int bid = blockIdx.x;
  int t0 = (bid & 3)*16, m0 = ((bid>>2)&7)*64, i0 = ((bid>>5)&3)*16, b = bid>>7;
  int tid = threadIdx.x;
  int tq = tid & 3, m = tid >> 2;         // 4 t-quads x 64 m
  for (int i = 0; i < 16; ++i){
    float4 v = *reinterpret_cast<const float4*>(
        x + ((size_t)(b*64 + i0 + i)*512 + (m0 + m))*64 + t0 + tq*4);
    lds[tq*4+0][i][m] = (bf16)v.x; lds[tq*4+1][i][m] = (bf16)v.y;
    lds[tq*4+2][i][m] = (bf16)v.z; lds[tq*4+3][i][m] = (bf16)v.w;
  }
  __syncthreads();
  for (int p = 0; p < 8; ++p){
    int row = p*32 + (tid >> 3); int t = row >> 4, i = row & 15, mc = tid & 7;
    bf16x8 v = *reinterpret_cast<const bf16x8*>(&lds[t][i][mc*8]);
    *reinterpret_cast<bf16x8*>(
        xmt + ((size_t)((b*64 + t0 + t)*64) + i0 + i)*512 + m0 + mc*8) = v;
  }
}

// ---------------- temporal conv (1x3) as tall GEMM; optional BN+relu on load
// in/out layout: [point=(b,n,t)][64ch]; block = one (b,n), 64 t x 64 o
__global__ __launch_bounds__(256,4) void k_conv(const bf16* __restrict__ in,
    const bf16* __restrict__ wp, bf16* __restrict__ outp, float* __restrict__ part,
    const float* __restrict__ sc, const float* __restrict__ sh){
  int tid = threadIdx.x, w = tid >> 6, l = tid & 63, l15 = l & 15, lg = l >> 4;
  int blk = blockIdx.x;
  size_t rowbase = (size_t)blk * 64;
  const bf16* xr = in + rowbase * 64;
  int t = w*16 + l15;
  f32x4 acc[4] = {};
  #pragma unroll
  for (int ks = 0; ks < 6; ++ks){
    int dt = ks >> 1, kh = ks & 1;
    int ts = t + dt - 1;
    bf16x8 a = {};
    if (ts >= 0 && ts < 64){
      a = *reinterpret_cast<const bf16x8*>(xr + ts*64 + kh*32 + lg*8);
      if (sc){                                  // BN1+relu applied on load
        int i0 = kh*32 + lg*8;
        #pragma unroll
        for (int e = 0; e < 8; ++e){
          float f = (float)a[e]*sc[i0+e] + sh[i0+e];
          a[e] = (bf16)fmaxf(f, 0.f);
        }
      }
    }
    #pragma unroll
    for (int cf = 0; cf < 4; ++cf){
      bf16x8 bfr = *reinterpret_cast<const bf16x8*>(wp + ((ks*4 + cf)*64 + l)*8);
      acc[cf] = MFMA16(a, bfr, acc[cf]);
    }
  }
  __shared__ float ssum[4][4][16], ssq[4][4][16];
  #pragma unroll
  for (int cf = 0; cf < 4; ++cf){
    int o = cf*16 + l15;
    float s = 0.f, q = 0.f;
    #pragma unroll
    for (int r = 0; r < 4; ++r){
      float vv = acc[cf][r];
      int to = w*16 + lg*4 + r;
      outp[(rowbase + to)*64 + o] = (bf16)vv;
      s += vv; q += vv*vv;
    }
    s += __shfl_xor(s, 16); s += __shfl_xor(s, 32);
    q += __shfl_xor(q, 16); q += __shfl_xor(q, 32);
    if (lg == 0){ ssum[w][cf][l15] = s; ssq[w][cf][l15] = q; }
  }
  __syncthreads();
  if (tid < 64){
    int cf = tid >> 4, c = tid & 15;
    float s = ssum[0][cf][c]+ssum[1][cf][c]+ssum[2][cf][c]+ssum[3][cf][c];
    float q = ssq[0][cf][c]+ssq[1][cf][c]+ssq[2][cf][c]+ssq[3][cf][c];
    part[(size_t)blk*128 + tid*2]     = s;
    part[(size_t)blk*128 + tid*2 + 1] = q;
  }
}

// ---------------- BN stats finalize: partials -> scale/shift ----------------
__global__ __launch_bounds__(256) void k_stats(const float* __restrict__ part, int nb,
    const float* __restrict__ g, const float* __restrict__ be,
    float* __restrict__ sc, float* __restrict__ sh){
  int c = blockIdx.x, tid = threadIdx.x;
  float s = 0.f, q = 0.f;
  for (int i = tid; i < nb; i += 256){
    s += part[(size_t)i*128 + c*2];
    q += part[(size_t)i*128 + c*2 + 1];
  }
  __shared__ float rs[256], rq[256];
  rs[tid] = s; rq[tid] = q; __syncthreads();
  for (int st = 128; st > 0; st >>= 1){
    if (tid < st){ rs[tid] += rs[tid+st]; rq[tid] += rq[tid+st]; }
    __syncthreads();
  }
  if (tid == 0){
    float cnt = (float)PP;
    float mean = rs[0]/cnt, var = rq[0]/cnt - mean*mean;
    float r = rsqrtf(var + EPSB);
    sc[c] = g[c]*r;
    sh[c] = be[c] - mean*g[c]*r;
  }
}

// ---------------- fused GEMM1+cheb: spm[(b,n,t)][o] ------------------------
// Per block: 128 j-rows (j=(b,t,i): 2 t x 64 i) x 128 n.  For each cheb k:
// main GEMM (sum over m, 16 ksteps, dbuf LDS) -> Vtile in acc; dump Vtile to
// swizzled LDS VT[n][j]; contract over i against cheb_w fragments -> acc2.
// Epilogue: acc2+cheb_b -> LDS repack -> coalesced bf16 store of spm.
__global__ __launch_bounds__(256,2) void k_gemm1(const bf16* __restrict__ xmt,
    const bf16* __restrict__ adjb, const bf16* __restrict__ cp,
    const float* __restrict__ cb, bf16* __restrict__ spm){
  __shared__ bf16 As[2][128*32];
  __shared__ bf16 Bs[2][128*32];
  __shared__ bf16 VT[128*128];          // [n][j] swizzled; reused as SP[256][64]

  int tid = threadIdx.x, w = tid >> 6, l = tid & 63, l15 = l & 15, lg = l >> 4;
  int wr = w >> 1, wc = w & 1;

  // bijective XCD swizzle over 2048 blocks; nt innermost (A-panel shared by 4)
  int orig = blockIdx.x;
  int wg = (orig & 7) * 256 + (orig >> 3);
  int jt = wg >> 2, nt = wg & 3;
  int J0 = jt*128, N0 = nt*128;

  const bf16* aglob = xmt + (size_t)J0*512;

  auto stage = [&](int buf, int m0, const bf16* bg){
    #pragma unroll
    for (int p = 0; p < 2; ++p){
      int idx = p*256 + tid;
      int r = idx >> 2, c = idx & 3;
      int cg = c ^ (r & 3);
      gload_lds16(aglob + (size_t)r*512 + m0 + cg*8,
                  &As[buf][(p*256 + w*64)*8]);
      gload_lds16(bg + (size_t)r*512 + m0 + cg*8,
                  &Bs[buf][(p*256 + w*64)*8]);
    }
  };

  f32x4 acc2[4][4] = {};
  const bf16* bglob = adjb + (size_t)N0*512;     // kk = 0
  stage(0, 0, bglob);
  __syncthreads();

  int buf = 0;
  int tw = w >> 1;                                // t_loc of this wave (cheb)
  for (int kk = 0; kk < 3; ++kk){
    f32x4 acc[4][4] = {};
    for (int ks = 0; ks < 16; ++ks){
      if (ks < 15) stage(buf ^ 1, (ks+1)*32, bglob);
      bf16x8 a[4], bb[4];
      #pragma unroll
      for (int rf = 0; rf < 4; ++rf){
        int row = wr*64 + rf*16 + l15;
        a[rf] = *reinterpret_cast<const bf16x8*>(
            &As[buf][row*32 + ((lg ^ (row & 3))*8)]);
      }
      #pragma unroll
      for (int cf = 0; cf < 4; ++cf){
        int row = wc*64 + cf*16 + l15;
        bb[cf] = *reinterpret_cast<const bf16x8*>(
            &Bs[buf][row*32 + ((lg ^ (row & 3))*8)]);
      }
      #pragma unroll
      for (int rf = 0; rf < 4; ++rf)
        #pragma unroll
        for (int cf = 0; cf < 4; ++cf)
          acc[rf][cf] = MFMA16(a[rf], bb[cf], acc[rf][cf]);
      __syncthreads();
      buf ^= 1;
    }

    // dump Vtile to VT[n][j], 16B-block-swizzled: block jb at jb^(n&15)
    #pragma unroll
    for (int rf = 0; rf < 4; ++rf){
      int jb = wr*8 + rf*2 + (lg >> 1);           // j0 = wr*64+rf*16+lg*4
      #pragma unroll
      for (int cf = 0; cf < 4; ++cf){
        int n = wc*64 + cf*16 + l15;
        bf16x4 pk;
        #pragma unroll
        for (int r = 0; r < 4; ++r) pk[r] = (bf16)acc[rf][cf][r];
        *reinterpret_cast<bf16x4*>(
            &VT[n*128 + ((jb ^ (n & 15)) << 3) + ((lg & 1) << 2)]) = pk;
      }
    }
    if (kk < 2){                                   // prefetch next k's tile 0
      bglob = adjb + ((size_t)(kk+1)*512 + N0)*512;
      stage(buf, 0, bglob);
    }
    __syncthreads();

    // cheb contraction: acc2[row=(t,n)][o] += VT^T(i) x cheb_w[kk]
    #pragma unroll
    for (int ks2 = 0; ks2 < 2; ++ks2){
      bf16x8 bc[4];
      #pragma unroll
      for (int cf = 0; cf < 4; ++cf)
        bc[cf] = *reinterpret_cast<const bf16x8*>(
            cp + (((kk*2 + ks2)*4 + cf)*64 + l)*8);
      #pragma unroll
      for (int rf = 0; rf < 4; ++rf){
        int n = (w & 1)*64 + rf*16 + l15;
        int jb = tw*8 + ks2*4 + lg;
        bf16x8 a2 = *reinterpret_cast<const bf16x8*>(
            &VT[n*128 + ((jb ^ (n & 15)) << 3)]);
        #pragma unroll
        for (int cf = 0; cf < 4; ++cf)
          acc2[rf][cf] = MFMA16(a2, bc[cf], acc2[rf][cf]);
      }
    }
    __syncthreads();                               // VT reads done; vmcnt drained
  }

  // epilogue: SP[row][o] = acc2 + cheb_b, then coalesced store
  bf16* SP = VT;
  float cbv[4];
  #pragma unroll
  for (int cf = 0; cf < 4; ++cf) cbv[cf] = cb[cf*16 + l15];
  #pragma unroll
  for (int rf = 0; rf < 4; ++rf){
    int rowb = w*64 + rf*16 + lg*4;
    #pragma unroll
    for (int cf = 0; cf < 4; ++cf){
      int o = cf*16 + l15;
      #pragma unroll
      for (int r = 0; r < 4; ++r)
        SP[(rowb + r)*64 + o] = (bf16)(acc2[rf][cf][r] + cbv[cf]);
    }
  }
  __syncthreads();
  int b = jt >> 5, t0 = (jt & 31)*2;
  #pragma unroll
  for (int q = 0; q < 8; ++q){
    int flat = q*256 + tid;                        // 2048 chunks of 8 elems
    int row = flat >> 3, oc = (flat & 7)*8;
    int tl = row >> 7, n = N0 + (row & 127);
    bf16x8 vv = *reinterpret_cast<const bf16x8*>(&SP[row*64 + oc]);
    *reinterpret_cast<bf16x8*>(
        &spm[(((size_t)b*512 + n)*64 + (t0 + tl))*64 + oc]) = vv;
  }
}

// ---------------- fusion: gate/res MFMA + combine; writes bf16 out_pre -----
__global__ __launch_bounds__(256,4) void k_fusion(const bf16* __restrict__ spm,
    const bf16* __restrict__ t2, const bf16* __restrict__ xlb,
    const bf16* __restrict__ gp, const bf16* __restrict__ rp,
    const float* __restrict__ sc2, const float* __restrict__ sh2,
    const float* __restrict__ gateb, bf16* __restrict__ pre,
    float* __restrict__ part){
  int tid = threadIdx.x, w = tid >> 6, l = tid & 63, l15 = l & 15, lg = l >> 4;
  int blk = blockIdx.x;
  int b = blk >> 9, n = blk & 511;
  size_t rowbase = (size_t)blk * 64;
  int t = w*16 + l15;
  f32x4 ag[4] = {}, ar[4] = {};
  #pragma unroll
  for (int ks = 0; ks < 4; ++ks){                 // gate: K=128 = [spatial|t2bn]
    bf16x8 a;
    if (ks < 2){
      a = *reinterpret_cast<const bf16x8*>(spm + (rowbase + t)*64 + ks*32 + lg*8);
    } else {
      int i0 = (ks-2)*32 + lg*8;
      bf16x8 raw = *reinterpret_cast<const bf16x8*>(t2 + (rowbase + t)*64 + i0);
      #pragma unroll
      for (int e = 0; e < 8; ++e){
        float f = (float)raw[e]*sc2[i0+e] + sh2[i0+e];
        a[e] = (bf16)fmaxf(f, 0.f);
      }
    }
    #pragma unroll
    for (int cf = 0; cf < 4; ++cf){
      bf16x8 bfr = *reinterpret_cast<const bf16x8*>(gp + ((ks*4 + cf)*64 + l)*8);
      ag[cf] = MFMA16(a, bfr, ag[cf]);
    }
  }
  #pragma unroll
  for (int ks = 0; ks < 2; ++ks){                 // res: K=64 on x
    bf16x8 a = *reinterpret_cast<const bf16x8*>(xlb + (rowbase + t)*64 + ks*32 + lg*8);
    #pragma unroll
    for (int cf = 0; cf < 4; ++cf){
      bf16x8 bfr = *reinterpret_cast<const bf16x8*>(rp + ((ks*4 + cf)*64 + l)*8);
      ar[cf] = MFMA16(a, bfr, ar[cf]);
    }
  }
  __shared__ float ssum[4][4][16], ssq[4][4][16];
  int tb = w*16 + lg*4;
  #pragma unroll
  for (int cf = 0; cf < 4; ++cf){
    int o = cf*16 + l15;
    float gb = gateb[o], sco = sc2[o], sho = sh2[o];
    float s = 0.f, q = 0.f;
    bf16x4 ov;
    #pragma unroll
    for (int r = 0; r < 4; ++r){
      size_t row = rowbase + tb + r;
      float z = ag[cf][r] + gb;
      float g = 1.f/(1.f + __expf(-z));
      float spv = (float)spm[row*64 + o];
      float tv  = (float)t2[row*64 + o];
      tv = fmaxf(tv*sco + sho, 0.f);
      float val = g*spv + (1.f - g)*tv + ar[cf][r];
      ov[r] = (bf16)val;
      s += val; q += val*val;
    }
    *reinterpret_cast<bf16x4*>(pre + (((size_t)b*64 + o)*512 + n)*64 + tb) = ov;
    s += __shfl_xor(s, 16); s += __shfl_xor(s, 32);
    q += __shfl_xor(q, 16); q += __shfl_xor(q, 32);
    if (lg == 0){ ssum[w][cf][l15] = s; ssq[w][cf][l15] = q; }
  }
  __syncthreads();
  if (tid < 64){
    int cf = tid >> 4, c = tid & 15;
    float s = ssum[0][cf][c]+ssum[1][cf][c]+ssum[2][cf][c]+ssum[3][cf][c];
    float q = ssq[0][cf][c]+ssq[1][cf][c]+ssq[2][cf][c]+ssq[3][cf][c];
    part[(size_t)blk*128 + tid*2]     = s;
    part[(size_t)blk*128 + tid*2 + 1] = q;
  }
}

// ---------------- BN3: read bf16 out_pre, write fp32 d_out ------------------
__global__ __launch_bounds__(256) void k_bn3(const bf16* __restrict__ pre,
    float* __restrict__ out,
    const float* __restrict__ sc, const float* __restrict__ sh){
  size_t total8 = (size_t)BB*CC*NN*TT/8;
  for (size_t i8 = (size_t)blockIdx.x*256 + threadIdx.x; i8 < total8;
       i8 += (size_t)gridDim.x*256){
    bf16x8 v = reinterpret_cast<const bf16x8*>(pre)[i8];
    int o = (int)(i8 >> 12) & 63;                  // n*t = 32768 per (b,o)
    float a = sc[o], bsh = sh[o];
    float4 r0, r1;
    r0.x = (float)v[0]*a + bsh; r0.y = (float)v[1]*a + bsh;
    r0.z = (float)v[2]*a + bsh; r0.w = (float)v[3]*a + bsh;
    r1.x = (float)v[4]*a + bsh; r1.y = (float)v[5]*a + bsh;
    r1.z = (float)v[6]*a + bsh; r1.w = (float)v[7]*a + bsh;
    reinterpret_cast<float4*>(out)[i8*2]     = r0;
    reinterpret_cast<float4*>(out)[i8*2 + 1] = r1;
  }
}

extern "C" void kernel_launch(void* const* d_in, const int* in_sizes, int n_in,
                              void* d_out, int out_size, void* d_ws, size_t ws_size,
                              hipStream_t stream){
  (void)in_sizes; (void)n_in; (void)out_size; (void)ws_size;
  const float* x   = (const float*)d_in[0];
  const float* adj = (const float*)d_in[1];
  const float* cw  = (const float*)d_in[2];
  const float* cb  = (const float*)d_in[3];
  const float* w1  = (const float*)d_in[4];
  // d_in[5] = b1 (cancels in BN1)
  const float* g1  = (const float*)d_in[6];
  const float* be1 = (const float*)d_in[7];
  const float* w2  = (const float*)d_in[8];
  // d_in[9] = b2 (cancels in BN2)
  const float* g2  = (const float*)d_in[10];
  const float* be2 = (const float*)d_in[11];
  const float* gw  = (const float*)d_in[12];
  const float* gb  = (const float*)d_in[13];
  const float* rw  = (const float*)d_in[14];
  // d_in[15] = res_b (cancels in BN3)
  const float* g3  = (const float*)d_in[16];
  const float* be3 = (const float*)d_in[17];
  float* out = (float*)d_out;

  char* ws = (char*)d_ws;
  size_t off = 0;
  auto alloc = [&](size_t bytes)->char*{
    char* p = ws + off; off += (bytes + 255) & ~(size_t)255; return p;
  };
  bf16* xlb  = (bf16*)alloc((size_t)PP*64*2);        // 67MB channel-last x
  bf16* xmt  = (bf16*)alloc((size_t)PP*64*2);        // 67MB; reused as out_pre
  bf16* t1   = (bf16*)alloc((size_t)PP*64*2);        // 67MB; reused as spm
  bf16* t2   = (bf16*)alloc((size_t)PP*64*2);        // 67MB
  bf16* spm  = t1;                                   // alias (t1 dead after conv2)
  bf16* pre  = xmt;                                  // alias (xmt dead after gemm1)
  bf16* adjb = (bf16*)alloc((size_t)KCH*512*512*2);
  bf16* w1p  = (bf16*)alloc(6*2048*2);
  bf16* w2p  = (bf16*)alloc(6*2048*2);
  bf16* cp   = (bf16*)alloc(6*2048*2);
  bf16* gp   = (bf16*)alloc(4*2048*2);
  bf16* rp   = (bf16*)alloc(2*2048*2);
  float* part = (float*)alloc((size_t)8192*128*4);   // shared partials (sequential)
  float* s1sc = (float*)alloc(256); float* s1sh = (float*)alloc(256);
  float* s2sc = (float*)alloc(256); float* s2sh = (float*)alloc(256);
  float* s3sc = (float*)alloc(256); float* s3sh = (float*)alloc(256);

  k_adjT <<<dim3(3072), dim3(256), 0, stream>>>(adj, adjb);
  k_wprep<<<dim3(1),    dim3(256), 0, stream>>>(w1, w2, cw, gw, rw, w1p, w2p, cp, gp, rp);
  k_xlb  <<<dim3(8192), dim3(256), 0, stream>>>(x, xlb);
  k_xmt  <<<dim3(2048), dim3(256), 0, stream>>>(x, xmt);

  k_conv <<<dim3(8192), dim3(256), 0, stream>>>(xlb, w1p, t1, part, nullptr, nullptr);
  k_stats<<<dim3(64),   dim3(256), 0, stream>>>(part, 8192, g1, be1, s1sc, s1sh);
  k_conv <<<dim3(8192), dim3(256), 0, stream>>>(t1, w2p, t2, part, s1sc, s1sh);
  k_stats<<<dim3(64),   dim3(256), 0, stream>>>(part, 8192, g2, be2, s2sc, s2sh);

  k_gemm1<<<dim3(2048), dim3(256), 0, stream>>>(xmt, adjb, cp, cb, spm);

  k_fusion<<<dim3(8192), dim3(256), 0, stream>>>(spm, t2, xlb, gp, rp,
                                                 s2sc, s2sh, gb, pre, part);
  k_stats<<<dim3(64),   dim3(256), 0, stream>>>(part, 8192, g3, be3, s3sc, s3sh);
  k_bn3  <<<dim3(2048), dim3(256), 0, stream>>>(pre, out, s3sc, s3sh);
}

// Round 4
// 622.966 us; speedup vs baseline: 1.5208x; 1.0016x over previous
//
#include <hip/hip_runtime.h>
#include <hip/hip_bf16.h>
#include <cstdint>

// Problem dims
#define BB 16
#define CC 64
#define NN 512
#define TT 64
#define KCH 3
#define PP (BB*NN*TT)      // 524288 points
#define EPSB 1e-5f

typedef __bf16 bf16;
typedef __bf16 bf16x8 __attribute__((ext_vector_type(8)));
typedef __bf16 bf16x4 __attribute__((ext_vector_type(4)));
typedef float  f32x4  __attribute__((ext_vector_type(4)));

#define MFMA16(A,Bv,Cv) __builtin_amdgcn_mfma_f32_16x16x32_bf16((A),(Bv),(Cv),0,0,0)

__device__ __forceinline__ void gload_lds16(const bf16* g, bf16* l){
  __builtin_amdgcn_global_load_lds(
      (const __attribute__((address_space(1))) void*)g,
      (__attribute__((address_space(3))) void*)l, 16, 0, 0);
}

// ---------------- prep: adjb[k][n][m] = bf16(adj[k][m][n]) ----------------
__global__ __launch_bounds__(256) void k_adjT(const float* __restrict__ adj,
                                              bf16* __restrict__ adjb){
  int idx = blockIdx.x*256 + threadIdx.x;          // over 3*512*512, exact grid
  int m = idx & 511, n = (idx >> 9) & 511, k = idx >> 18;
  adjb[idx] = (bf16)adj[((size_t)(k*512 + m))*512 + n];
}

// ---------------- prep: weights into MFMA B-fragment layout ----------------
// consumer reads: frag elem j of lane l at step ks, colfrag cf:
//   B[k = ks*32 + (l>>4)*8 + j][col = cf*16 + (l&15)]
// stored at wp[(((ks*4+cf)*64 + l)*8 + j]
__global__ __launch_bounds__(256) void k_wprep(const float* __restrict__ w1,
    const float* __restrict__ w2, const float* __restrict__ cw,
    const float* __restrict__ gw, const float* __restrict__ rw,
    bf16* __restrict__ w1p, bf16* __restrict__ w2p, bf16* __restrict__ cp,
    bf16* __restrict__ gp, bf16* __restrict__ rp){
  int tid = threadIdx.x;
  for (int e = tid; e < 6*2048; e += 256){          // K=192 groups (conv & cheb)
    int j = e&7, lane = (e>>3)&63, cf = (e>>9)&3, ks = e>>11;
    int k = ks*32 + (lane>>4)*8 + j, col = cf*16 + (lane&15);
    int kk = k >> 6, i = k & 63;                    // (dt|chebk, channel)
    w1p[e] = (bf16)w1[(col*64 + i)*3 + kk];         // w1[o][i][dt]
    w2p[e] = (bf16)w2[(col*64 + i)*3 + kk];
    cp[e]  = (bf16)cw[((size_t)kk*64 + i)*64 + col];// cheb_w[k][i][o]
  }
  for (int e = tid; e < 4*2048; e += 256){          // K=128 (gate)
    int j = e&7, lane = (e>>3)&63, cf = (e>>9)&3, ks = e>>11;
    int k = ks*32 + (lane>>4)*8 + j, col = cf*16 + (lane&15);
    gp[e] = (bf16)gw[col*128 + k];                  // gate_w[g][c]
  }
  for (int e = tid; e < 2*2048; e += 256){          // K=64 (res)
    int j = e&7, lane = (e>>3)&63, cf = (e>>9)&3, ks = e>>11;
    int k = ks*32 + (lane>>4)*8 + j, col = cf*16 + (lane&15);
    rp[e] = (bf16)rw[col*64 + k];                   // res_w[o][i]
  }
}

// ---------------- prep: xlb[b][n][t][i] = bf16(x[b][i][n][t]) --------------
__global__ __launch_bounds__(256) void k_xlb(const float* __restrict__ x,
                                             bf16* __restrict__ xlb){
  __shared__ float tile[64][65];
  int bn = blockIdx.x; int b = bn >> 9, n = bn & 511;
  int tid = threadIdx.x;
  const float* xp = x + ((size_t)(b*64)*512 + n)*64;   // x[b][0][n][0]
  for (int p = 0; p < 4; ++p){
    int q = p*256 + tid;                  // quad id 0..1023
    int i = q >> 4, tc = (q & 15)*4;
    float4 v = *reinterpret_cast<const float4*>(xp + (size_t)i*512*64 + tc);
    tile[i][tc+0] = v.x; tile[i][tc+1] = v.y; tile[i][tc+2] = v.z; tile[i][tc+3] = v.w;
  }
  __syncthreads();
  bf16* op = xlb + (size_t)bn*4096;
  for (int p = 0; p < 2; ++p){
    int v8 = p*256 + tid;                 // 0..511
    int t = v8 >> 3, ic = (v8 & 7)*8;
    bf16x8 o;
    #pragma unroll
    for (int e = 0; e < 8; ++e) o[e] = (bf16)tile[ic+e][t];
    *reinterpret_cast<bf16x8*>(op + t*64 + ic) = o;
  }
}

// ---------------- prep: xmt[b][t][i][m] = bf16(x[b][i][m][t]) --------------
// tile: i:16, m:64, t:16
__global__ __launch_bounds__(256) void k_xmt(const float* __restrict__ x,
                                             bf16* __restrict__ xmt){
  __shared__ bf16 lds[16][16][72];        // [t][i][m+pad]
  int bid = blockIdx.x;
  int t0 = (bid & 3)*16, m0 = ((bid>>2)&7)*64, i0 = ((bid>>5)&3)*16, b = bid>>7;
  int tid = threadIdx.x;
  int tq = tid & 3, m = tid >> 2;         // 4 t-quads x 64 m
  for (int i = 0; i < 16; ++i){
    float4 v = *reinterpret_cast<const float4*>(
        x + ((size_t)(b*64 + i0 + i)*512 + (m0 + m))*64 + t0 + tq*4);
    lds[tq*4+0][i][m] = (bf16)v.x; lds[tq*4+1][i][m] = (bf16)v.y;
    lds[tq*4+2][i][m] = (bf16)v.z; lds[tq*4+3][i][m] = (bf16)v.w;
  }
  __syncthreads();
  for (int p = 0; p < 8; ++p){
    int row = p*32 + (tid >> 3); int t = row >> 4, i = row & 15, mc = tid & 7;
    bf16x8 v = *reinterpret_cast<const bf16x8*>(&lds[t][i][mc*8]);
    *reinterpret_cast<bf16x8*>(
        xmt + ((size_t)((b*64 + t0 + t)*64) + i0 + i)*512 + m0 + mc*8) = v;
  }
}

// ---------------- temporal conv (1x3) as tall GEMM; optional BN+relu on load
// in/out layout: [point=(b,n,t)][64ch]; block = one (b,n), 64 t x 64 o
__global__ __launch_bounds__(256,4) void k_conv(const bf16* __restrict__ in,
    const bf16* __restrict__ wp, bf16* __restrict__ outp, float* __restrict__ part,
    const float* __restrict__ sc, const float* __restrict__ sh){
  int tid = threadIdx.x, w = tid >> 6, l = tid & 63, l15 = l & 15, lg = l >> 4;
  int blk = blockIdx.x;
  size_t rowbase = (size_t)blk * 64;
  const bf16* xr = in + rowbase * 64;
  int t = w*16 + l15;
  f32x4 acc[4] = {};
  #pragma unroll
  for (int ks = 0; ks < 6; ++ks){
    int dt = ks >> 1, kh = ks & 1;
    int ts = t + dt - 1;
    bf16x8 a = {};
    if (ts >= 0 && ts < 64){
      a = *reinterpret_cast<const bf16x8*>(xr + ts*64 + kh*32 + lg*8);
      if (sc){                                  // BN1+relu applied on load
        int i0 = kh*32 + lg*8;
        #pragma unroll
        for (int e = 0; e < 8; ++e){
          float f = (float)a[e]*sc[i0+e] + sh[i0+e];
          a[e] = (bf16)fmaxf(f, 0.f);
        }
      }
    }
    #pragma unroll
    for (int cf = 0; cf < 4; ++cf){
      bf16x8 bfr = *reinterpret_cast<const bf16x8*>(wp + ((ks*4 + cf)*64 + l)*8);
      acc[cf] = MFMA16(a, bfr, acc[cf]);
    }
  }
  __shared__ float ssum[4][4][16], ssq[4][4][16];
  #pragma unroll
  for (int cf = 0; cf < 4; ++cf){
    int o = cf*16 + l15;
    float s = 0.f, q = 0.f;
    #pragma unroll
    for (int r = 0; r < 4; ++r){
      float vv = acc[cf][r];
      int to = w*16 + lg*4 + r;
      outp[(rowbase + to)*64 + o] = (bf16)vv;
      s += vv; q += vv*vv;
    }
    s += __shfl_xor(s, 16); s += __shfl_xor(s, 32);
    q += __shfl_xor(q, 16); q += __shfl_xor(q, 32);
    if (lg == 0){ ssum[w][cf][l15] = s; ssq[w][cf][l15] = q; }
  }
  __syncthreads();
  if (tid < 64){
    int cf = tid >> 4, c = tid & 15;
    float s = ssum[0][cf][c]+ssum[1][cf][c]+ssum[2][cf][c]+ssum[3][cf][c];
    float q = ssq[0][cf][c]+ssq[1][cf][c]+ssq[2][cf][c]+ssq[3][cf][c];
    part[(size_t)blk*128 + tid*2]     = s;
    part[(size_t)blk*128 + tid*2 + 1] = q;
  }
}

// ---------------- BN stats finalize: partials -> scale/shift ----------------
__global__ __launch_bounds__(256) void k_stats(const float* __restrict__ part, int nb,
    const float* __restrict__ g, const float* __restrict__ be,
    float* __restrict__ sc, float* __restrict__ sh){
  int c = blockIdx.x, tid = threadIdx.x;
  float s = 0.f, q = 0.f;
  for (int i = tid; i < nb; i += 256){
    s += part[(size_t)i*128 + c*2];
    q += part[(size_t)i*128 + c*2 + 1];
  }
  __shared__ float rs[256], rq[256];
  rs[tid] = s; rq[tid] = q; __syncthreads();
  for (int st = 128; st > 0; st >>= 1){
    if (tid < st){ rs[tid] += rs[tid+st]; rq[tid] += rq[tid+st]; }
    __syncthreads();
  }
  if (tid == 0){
    float cnt = (float)PP;
    float mean = rs[0]/cnt, var = rq[0]/cnt - mean*mean;
    float r = rsqrtf(var + EPSB);
    sc[c] = g[c]*r;
    sh[c] = be[c] - mean*g[c]*r;
  }
}

// ---------------- fused GEMM1+cheb: spm[(b,n,t)][o] ------------------------
// Per block: 128 j-rows (j=(b,t,i): 2 t x 64 i) x 128 n.  For each cheb k:
// main GEMM over m: 16 K-steps, TRIPLE-buffered LDS, 2-deep prefetch with
// counted vmcnt (never 0 mid-loop) + raw s_barrier (T4). Then Vtile -> VT
// (swizzled LDS), cheb contraction over i -> acc2. Epilogue: repack + store.
__global__ __launch_bounds__(256,2) void k_gemm1(const bf16* __restrict__ xmt,
    const bf16* __restrict__ adjb, const bf16* __restrict__ cp,
    const float* __restrict__ cb, bf16* __restrict__ spm){
  __shared__ bf16 As[3][128*32];
  __shared__ bf16 Bs[3][128*32];
  __shared__ bf16 VT[128*128];          // [n][j] swizzled; reused as SP[256][64]

  int tid = threadIdx.x, w = tid >> 6, l = tid & 63, l15 = l & 15, lg = l >> 4;
  int wr = w >> 1, wc = w & 1;

  // bijective XCD swizzle over 2048 blocks; nt innermost (A-panel shared by 4)
  int orig = blockIdx.x;
  int wg = (orig & 7) * 256 + (orig >> 3);
  int jt = wg >> 2, nt = wg & 3;
  int J0 = jt*128, N0 = nt*128;

  const bf16* aglob = xmt + (size_t)J0*512;

  // 4 gload instructions per stage call (vmcnt +4)
  auto stage = [&](int buf, int m0, const bf16* bg){
    #pragma unroll
    for (int p = 0; p < 2; ++p){
      int idx = p*256 + tid;
      int r = idx >> 2, c = idx & 3;
      int cg = c ^ (r & 3);
      gload_lds16(aglob + (size_t)r*512 + m0 + cg*8,
                  &As[buf][(p*256 + w*64)*8]);
      gload_lds16(bg + (size_t)r*512 + m0 + cg*8,
                  &Bs[buf][(p*256 + w*64)*8]);
    }
  };

  f32x4 acc2[4][4] = {};
  const bf16* bglob = adjb + (size_t)N0*512;     // kk = 0
  stage(0, 0, bglob);
  stage(1, 32, bglob);

  int tw = w >> 1;                                // t_loc of this wave (cheb)
  for (int kk = 0; kk < 3; ++kk){
    f32x4 acc[4][4] = {};
    for (int ks = 0; ks < 16; ++ks){
      // 2-deep prefetch: tile ks+2 into buffer (ks+2)%3
      if (ks <= 13) stage((ks+2)%3, (ks+2)*32, bglob);
      // counted vmcnt: in-flight tiles beyond ks = {ks+1, ks+2} -> 8 loads
      if (ks <= 13)      asm volatile("s_waitcnt vmcnt(8)" ::: "memory");
      else if (ks == 14) asm volatile("s_waitcnt vmcnt(4)" ::: "memory");
      else               asm volatile("s_waitcnt vmcnt(0)" ::: "memory");
      __builtin_amdgcn_s_barrier();
      __builtin_amdgcn_sched_barrier(0);

      int cbuf = ks % 3;
      bf16x8 a[4], bb[4];
      #pragma unroll
      for (int rf = 0; rf < 4; ++rf){
        int row = wr*64 + rf*16 + l15;
        a[rf] = *reinterpret_cast<const bf16x8*>(
            &As[cbuf][row*32 + ((lg ^ (row & 3))*8)]);
      }
      #pragma unroll
      for (int cf = 0; cf < 4; ++cf){
        int row = wc*64 + cf*16 + l15;
        bb[cf] = *reinterpret_cast<const bf16x8*>(
            &Bs[cbuf][row*32 + ((lg ^ (row & 3))*8)]);
      }
      #pragma unroll
      for (int rf = 0; rf < 4; ++rf)
        #pragma unroll
        for (int cf = 0; cf < 4; ++cf)
          acc[rf][cf] = MFMA16(a[rf], bb[cf], acc[rf][cf]);

      // ds_reads retired before next iter's stage may overwrite this buffer
      asm volatile("s_waitcnt lgkmcnt(0)" ::: "memory");
      __builtin_amdgcn_sched_barrier(0);
      __builtin_amdgcn_s_barrier();
    }

    // dump Vtile to VT[n][j], 16B-block-swizzled: block jb at jb^(n&15)
    #pragma unroll
    for (int rf = 0; rf < 4; ++rf){
      int jb = wr*8 + rf*2 + (lg >> 1);           // j0 = wr*64+rf*16+lg*4
      #pragma unroll
      for (int cf = 0; cf < 4; ++cf){
        int n = wc*64 + cf*16 + l15;
        bf16x4 pk;
        #pragma unroll
        for (int r = 0; r < 4; ++r) pk[r] = (bf16)acc[rf][cf][r];
        *reinterpret_cast<bf16x4*>(
            &VT[n*128 + ((jb ^ (n & 15)) << 3) + ((lg & 1) << 2)]) = pk;
      }
    }
    if (kk < 2){                       // prefetch next kk tiles 0,1 (overlaps cheb)
      bglob = adjb + ((size_t)(kk+1)*512 + N0)*512;
      stage(0, 0, bglob);
      stage(1, 32, bglob);
    }
    // VT writes visible to all waves; do NOT drain vmcnt (prefetch survives)
    asm volatile("s_waitcnt lgkmcnt(0)" ::: "memory");
    __builtin_amdgcn_sched_barrier(0);
    __builtin_amdgcn_s_barrier();

    // cheb contraction: acc2[row=(t,n)][o] += VT^T(i) x cheb_w[kk]
    #pragma unroll
    for (int ks2 = 0; ks2 < 2; ++ks2){
      bf16x8 bc[4];
      #pragma unroll
      for (int cf = 0; cf < 4; ++cf)
        bc[cf] = *reinterpret_cast<const bf16x8*>(
            cp + (((kk*2 + ks2)*4 + cf)*64 + l)*8);
      #pragma unroll
      for (int rf = 0; rf < 4; ++rf){
        int n = (w & 1)*64 + rf*16 + l15;
        int jb = tw*8 + ks2*4 + lg;
        bf16x8 a2 = *reinterpret_cast<const bf16x8*>(
            &VT[n*128 + ((jb ^ (n & 15)) << 3)]);
        #pragma unroll
        for (int cf = 0; cf < 4; ++cf)
          acc2[rf][cf] = MFMA16(a2, bc[cf], acc2[rf][cf]);
      }
    }
    // VT reads retired before next kk's dump overwrites VT; keep vmcnt intact
    asm volatile("s_waitcnt lgkmcnt(0)" ::: "memory");
    __builtin_amdgcn_sched_barrier(0);
    __builtin_amdgcn_s_barrier();
  }

  // epilogue: SP[row][o] = acc2 + cheb_b, then coalesced store
  bf16* SP = VT;
  float cbv[4];
  #pragma unroll
  for (int cf = 0; cf < 4; ++cf) cbv[cf] = cb[cf*16 + l15];
  #pragma unroll
  for (int rf = 0; rf < 4; ++rf){
    int rowb = w*64 + rf*16 + lg*4;
    #pragma unroll
    for (int cf = 0; cf < 4; ++cf){
      int o = cf*16 + l15;
      #pragma unroll
      for (int r = 0; r < 4; ++r)
        SP[(rowb + r)*64 + o] = (bf16)(acc2[rf][cf][r] + cbv[cf]);
    }
  }
  __syncthreads();
  int b = jt >> 5, t0 = (jt & 31)*2;
  #pragma unroll
  for (int q = 0; q < 8; ++q){
    int flat = q*256 + tid;                        // 2048 chunks of 8 elems
    int row = flat >> 3, oc = (flat & 7)*8;
    int tl = row >> 7, n = N0 + (row & 127);
    bf16x8 vv = *reinterpret_cast<const bf16x8*>(&SP[row*64 + oc]);
    *reinterpret_cast<bf16x8*>(
        &spm[(((size_t)b*512 + n)*64 + (t0 + tl))*64 + oc]) = vv;
  }
}

// ---------------- fusion: gate/res MFMA + combine; writes bf16 out_pre -----
__global__ __launch_bounds__(256,4) void k_fusion(const bf16* __restrict__ spm,
    const bf16* __restrict__ t2, const bf16* __restrict__ xlb,
    const bf16* __restrict__ gp, const bf16* __restrict__ rp,
    const float* __restrict__ sc2, const float* __restrict__ sh2,
    const float* __restrict__ gateb, bf16* __restrict__ pre,
    float* __restrict__ part){
  int tid = threadIdx.x, w = tid >> 6, l = tid & 63, l15 = l & 15, lg = l >> 4;
  int blk = blockIdx.x;
  int b = blk >> 9, n = blk & 511;
  size_t rowbase = (size_t)blk * 64;
  int t = w*16 + l15;
  f32x4 ag[4] = {}, ar[4] = {};
  #pragma unroll
  for (int ks = 0; ks < 4; ++ks){                 // gate: K=128 = [spatial|t2bn]
    bf16x8 a;
    if (ks < 2){
      a = *reinterpret_cast<const bf16x8*>(spm + (rowbase + t)*64 + ks*32 + lg*8);
    } else {
      int i0 = (ks-2)*32 + lg*8;
      bf16x8 raw = *reinterpret_cast<const bf16x8*>(t2 + (rowbase + t)*64 + i0);
      #pragma unroll
      for (int e = 0; e < 8; ++e){
        float f = (float)raw[e]*sc2[i0+e] + sh2[i0+e];
        a[e] = (bf16)fmaxf(f, 0.f);
      }
    }
    #pragma unroll
    for (int cf = 0; cf < 4; ++cf){
      bf16x8 bfr = *reinterpret_cast<const bf16x8*>(gp + ((ks*4 + cf)*64 + l)*8);
      ag[cf] = MFMA16(a, bfr, ag[cf]);
    }
  }
  #pragma unroll
  for (int ks = 0; ks < 2; ++ks){                 // res: K=64 on x
    bf16x8 a = *reinterpret_cast<const bf16x8*>(xlb + (rowbase + t)*64 + ks*32 + lg*8);
    #pragma unroll
    for (int cf = 0; cf < 4; ++cf){
      bf16x8 bfr = *reinterpret_cast<const bf16x8*>(rp + ((ks*4 + cf)*64 + l)*8);
      ar[cf] = MFMA16(a, bfr, ar[cf]);
    }
  }
  __shared__ float ssum[4][4][16], ssq[4][4][16];
  int tb = w*16 + lg*4;
  #pragma unroll
  for (int cf = 0; cf < 4; ++cf){
    int o = cf*16 + l15;
    float gb = gateb[o], sco = sc2[o], sho = sh2[o];
    float s = 0.f, q = 0.f;
    bf16x4 ov;
    #pragma unroll
    for (int r = 0; r < 4; ++r){
      size_t row = rowbase + tb + r;
      float z = ag[cf][r] + gb;
      float g = 1.f/(1.f + __expf(-z));
      float spv = (float)spm[row*64 + o];
      float tv  = (float)t2[row*64 + o];
      tv = fmaxf(tv*sco + sho, 0.f);
      float val = g*spv + (1.f - g)*tv + ar[cf][r];
      ov[r] = (bf16)val;
      s += val; q += val*val;
    }
    *reinterpret_cast<bf16x4*>(pre + (((size_t)b*64 + o)*512 + n)*64 + tb) = ov;
    s += __shfl_xor(s, 16); s += __shfl_xor(s, 32);
    q += __shfl_xor(q, 16); q += __shfl_xor(q, 32);
    if (lg == 0){ ssum[w][cf][l15] = s; ssq[w][cf][l15] = q; }
  }
  __syncthreads();
  if (tid < 64){
    int cf = tid >> 4, c = tid & 15;
    float s = ssum[0][cf][c]+ssum[1][cf][c]+ssum[2][cf][c]+ssum[3][cf][c];
    float q = ssq[0][cf][c]+ssq[1][cf][c]+ssq[2][cf][c]+ssq[3][cf][c];
    part[(size_t)blk*128 + tid*2]     = s;
    part[(size_t)blk*128 + tid*2 + 1] = q;
  }
}

// ---------------- BN3: read bf16 out_pre, write fp32 d_out ------------------
__global__ __launch_bounds__(256) void k_bn3(const bf16* __restrict__ pre,
    float* __restrict__ out,
    const float* __restrict__ sc, const float* __restrict__ sh){
  size_t total8 = (size_t)BB*CC*NN*TT/8;
  for (size_t i8 = (size_t)blockIdx.x*256 + threadIdx.x; i8 < total8;
       i8 += (size_t)gridDim.x*256){
    bf16x8 v = reinterpret_cast<const bf16x8*>(pre)[i8];
    int o = (int)(i8 >> 12) & 63;                  // n*t = 32768 per (b,o)
    float a = sc[o], bsh = sh[o];
    float4 r0, r1;
    r0.x = (float)v[0]*a + bsh; r0.y = (float)v[1]*a + bsh;
    r0.z = (float)v[2]*a + bsh; r0.w = (float)v[3]*a + bsh;
    r1.x = (float)v[4]*a + bsh; r1.y = (float)v[5]*a + bsh;
    r1.z = (float)v[6]*a + bsh; r1.w = (float)v[7]*a + bsh;
    reinterpret_cast<float4*>(out)[i8*2]     = r0;
    reinterpret_cast<float4*>(out)[i8*2 + 1] = r1;
  }
}

extern "C" void kernel_launch(void* const* d_in, const int* in_sizes, int n_in,
                              void* d_out, int out_size, void* d_ws, size_t ws_size,
                              hipStream_t stream){
  (void)in_sizes; (void)n_in; (void)out_size; (void)ws_size;
  const float* x   = (const float*)d_in[0];
  const float* adj = (const float*)d_in[1];
  const float* cw  = (const float*)d_in[2];
  const float* cb  = (const float*)d_in[3];
  const float* w1  = (const float*)d_in[4];
  // d_in[5] = b1 (cancels in BN1)
  const float* g1  = (const float*)d_in[6];
  const float* be1 = (const float*)d_in[7];
  const float* w2  = (const float*)d_in[8];
  // d_in[9] = b2 (cancels in BN2)
  const float* g2  = (const float*)d_in[10];
  const float* be2 = (const float*)d_in[11];
  const float* gw  = (const float*)d_in[12];
  const float* gb  = (const float*)d_in[13];
  const float* rw  = (const float*)d_in[14];
  // d_in[15] = res_b (cancels in BN3)
  const float* g3  = (const float*)d_in[16];
  const float* be3 = (const float*)d_in[17];
  float* out = (float*)d_out;

  char* ws = (char*)d_ws;
  size_t off = 0;
  auto alloc = [&](size_t bytes)->char*{
    char* p = ws + off; off += (bytes + 255) & ~(size_t)255; return p;
  };
  bf16* xlb  = (bf16*)alloc((size_t)PP*64*2);        // 67MB channel-last x
  bf16* xmt  = (bf16*)alloc((size_t)PP*64*2);        // 67MB; reused as out_pre
  bf16* t1   = (bf16*)alloc((size_t)PP*64*2);        // 67MB; reused as spm
  bf16* t2   = (bf16*)alloc((size_t)PP*64*2);        // 67MB
  bf16* spm  = t1;                                   // alias (t1 dead after conv2)
  bf16* pre  = xmt;                                  // alias (xmt dead after gemm1)
  bf16* adjb = (bf16*)alloc((size_t)KCH*512*512*2);
  bf16* w1p  = (bf16*)alloc(6*2048*2);
  bf16* w2p  = (bf16*)alloc(6*2048*2);
  bf16* cp   = (bf16*)alloc(6*2048*2);
  bf16* gp   = (bf16*)alloc(4*2048*2);
  bf16* rp   = (bf16*)alloc(2*2048*2);
  float* part = (float*)alloc((size_t)8192*128*4);   // shared partials (sequential)
  float* s1sc = (float*)alloc(256); float* s1sh = (float*)alloc(256);
  float* s2sc = (float*)alloc(256); float* s2sh = (float*)alloc(256);
  float* s3sc = (float*)alloc(256); float* s3sh = (float*)alloc(256);

  k_adjT <<<dim3(3072), dim3(256), 0, stream>>>(adj, adjb);
  k_wprep<<<dim3(1),    dim3(256), 0, stream>>>(w1, w2, cw, gw, rw, w1p, w2p, cp, gp, rp);
  k_xlb  <<<dim3(8192), dim3(256), 0, stream>>>(x, xlb);
  k_xmt  <<<dim3(2048), dim3(256), 0, stream>>>(x, xmt);

  k_conv <<<dim3(8192), dim3(256), 0, stream>>>(xlb, w1p, t1, part, nullptr, nullptr);
  k_stats<<<dim3(64),   dim3(256), 0, stream>>>(part, 8192, g1, be1, s1sc, s1sh);
  k_conv <<<dim3(8192), dim3(256), 0, stream>>>(t1, w2p, t2, part, s1sc, s1sh);
  k_stats<<<dim3(64),   dim3(256), 0, stream>>>(part, 8192, g2, be2, s2sc, s2sh);

  k_gemm1<<<dim3(2048), dim3(256), 0, stream>>>(xmt, adjb, cp, cb, spm);

  k_fusion<<<dim3(8192), dim3(256), 0, stream>>>(spm, t2, xlb, gp, rp,
                                                 s2sc, s2sh, gb, pre, part);
  k_stats<<<dim3(64),   dim3(256), 0, stream>>>(part, 8192, g3, be3, s3sc, s3sh);
  k_bn3  <<<dim3(2048), dim3(256), 0, stream>>>(pre, out, s3sc, s3sh);
}